// Round 1
// baseline (1663.324 us; speedup 1.0000x reference)
//
#include <hip/hip_runtime.h>
#include <math.h>

#define NB 64
#define NMAXC 256
#define TC 16
#define HC 32
#define NNODES 16384
#define NEDGES 131072

static inline int GRID(int n) { return (n + 255) / 256; }

// ---------------- GCN conv ----------------

__global__ void k_init_deg(float* deg) {
    int i = blockIdx.x * 256 + threadIdx.x;
    if (i < NNODES) deg[i] = 1.0f;   // self-loop weight
}

__global__ void k_edge_deg(const int* __restrict__ dst, const float* __restrict__ ew,
                           float* __restrict__ deg) {
    int e = blockIdx.x * 256 + threadIdx.x;
    if (e < NEDGES) atomicAdd(&deg[dst[e]], ew[e]);
}

__global__ void k_rsqrt(float* deg) {
    int i = blockIdx.x * 256 + threadIdx.x;
    if (i < NNODES) { float d = deg[i]; deg[i] = (d > 0.f) ? rsqrtf(d) : 0.f; }
}

__global__ void k_xw(const float* __restrict__ pos, const float* __restrict__ W1,
                     float* __restrict__ xw) {
    int idx = blockIdx.x * 256 + threadIdx.x;
    if (idx >= NNODES * TC * HC) return;
    int h = idx & 31;
    int row = idx >> 5;                 // n*T + t
    const float* p = pos + (size_t)row * 3;
    xw[idx] = p[0] * W1[h] + p[1] * W1[32 + h] + p[2] * W1[64 + h];
}

// one block per edge, 256 threads, 2 features each
__global__ void k_scatter(const int* __restrict__ src, const int* __restrict__ dst,
                          const float* __restrict__ ew, const float* __restrict__ dinv,
                          const float* __restrict__ xw, float* __restrict__ y) {
    int e = blockIdx.x;
    int t = threadIdx.x;
    int s = src[e], d = dst[e];
    float coef = dinv[s] * ew[e] * dinv[d];
    const float* xs = xw + (size_t)s * 512;
    float* yd = y + (size_t)d * 512;
    atomicAdd(&yd[t], xs[t] * coef);
    atomicAdd(&yd[t + 256], xs[t + 256] * coef);
}

__global__ void k_finalize(float* __restrict__ y, const float* __restrict__ xw,
                           const float* __restrict__ dinv, const float* __restrict__ b1) {
    int idx = blockIdx.x * 256 + threadIdx.x;
    if (idx >= NNODES * 512) return;
    int h = idx & 31;
    int n = idx >> 9;
    float dv = dinv[n];
    float v = y[idx] + xw[idx] * dv * dv + b1[h];
    y[idx] = fmaxf(v, 0.0f);
}

__global__ void k_adj(const int* __restrict__ src, const int* __restrict__ dst,
                      float* __restrict__ adj) {
    int e = blockIdx.x * 256 + threadIdx.x;
    if (e >= NEDGES) return;
    int s = src[e], d = dst[e];
    int g = s >> 8;
    atomicAdd(&adj[((size_t)g << 16) + ((size_t)(s & 255) << 8) + (size_t)(d & 255)], 1.0f);
}

// ---------------- generic per-level kernels ----------------

// xm[r,h] = mean_t x[b*sb + t*st + n*sn + h],  r = b*Nc+n
__global__ void k_mean_t(const float* __restrict__ x, float* __restrict__ xm,
                         int Nc, int sb, int st, int sn) {
    int idx = blockIdx.x * 256 + threadIdx.x;
    int total = NB * Nc * HC;
    if (idx >= total) return;
    int h = idx & 31;
    int r = idx >> 5;
    int b = r / Nc, n = r % Nc;
    const float* p = x + (size_t)b * sb + (size_t)n * sn + h;
    float s = 0.f;
    for (int t = 0; t < TC; ++t) s += p[(size_t)t * st];
    xm[idx] = s * (1.0f / TC);
}

// one 64-lane wave per row: s = tanh(xm@Wp + bp), p = softmax_k(s)
__global__ void k_s_softmax(const float* __restrict__ xm, const float* __restrict__ Wp,
                            const float* __restrict__ bp, float* __restrict__ p, int Kc) {
    int r = blockIdx.x;
    int k = threadIdx.x;
    const float* xr = xm + (size_t)r * HC;
    float v = -1e30f;
    if (k < Kc) {
        float acc = bp[k];
        for (int h = 0; h < HC; ++h) acc += xr[h] * Wp[h * Kc + k];
        v = tanhf(acc);
    }
    float m = v;
    for (int o = 32; o > 0; o >>= 1) m = fmaxf(m, __shfl_xor(m, o));
    float e = (k < Kc) ? expf(v - m) : 0.f;
    float s = e;
    for (int o = 32; o > 0; o >>= 1) s += __shfl_xor(s, o);
    if (k < Kc) p[(size_t)r * Kc + k] = e / s;
}

// out[b,t,k,h] = sum_n p[(b*Nc+n)*Kc+k] * x[b*sb + t*st + n*sn + h]
__global__ void k_pool_x(const float* __restrict__ p, const float* __restrict__ x,
                         float* __restrict__ outp, int Nc, int Kc, int sb, int st, int sn) {
    int idx = blockIdx.x * 256 + threadIdx.x;
    int total = NB * TC * Kc * HC;
    if (idx >= total) return;
    int h = idx & 31;
    int rest = idx >> 5;
    int k = rest % Kc;
    int bt = rest / Kc;
    int b = bt / TC, t = bt % TC;
    const float* xp = x + (size_t)b * sb + (size_t)t * st + h;
    const float* pp = p + (size_t)b * Nc * Kc + k;
    float acc = 0.f;
    for (int n = 0; n < Nc; ++n) acc += pp[(size_t)n * Kc] * xp[(size_t)n * sn];
    outp[idx] = acc;
}

__global__ void k_dflat(const float* __restrict__ adj, float* __restrict__ dflat, int Nc) {
    int idx = blockIdx.x * 256 + threadIdx.x;
    if (idx >= NB * Nc) return;
    const float* a = adj + (size_t)idx * Nc;
    float s = 0.f;
    for (int m = 0; m < Nc; ++m) s += a[m];
    dflat[idx] = s;
}

// tmp[b,n,l] = sum_m adj[b,n,m] * p[(b*Nc+m)*Kc+l]
__global__ void k_adj_p(const float* __restrict__ adj, const float* __restrict__ p,
                        float* __restrict__ tmp, int Nc, int Kc) {
    int idx = blockIdx.x * 256 + threadIdx.x;
    int total = NB * Nc * Kc;
    if (idx >= total) return;
    int l = idx % Kc;
    int n = (idx / Kc) % Nc;
    int b = idx / (Kc * Nc);
    const float* a = adj + ((size_t)b * Nc + n) * Nc;
    const float* pp = p + (size_t)b * Nc * Kc + l;
    float s = 0.f;
    for (int m = 0; m < Nc; ++m) s += a[m] * pp[(size_t)m * Kc];
    tmp[idx] = s;
}

// oadj[b,k,l] = sum_n p[(b*Nc+n)*Kc+k] * tmp[b,n,l]
__global__ void k_pT_tmp(const float* __restrict__ p, const float* __restrict__ tmp,
                         float* __restrict__ oadj, int Nc, int Kc) {
    int idx = blockIdx.x * 256 + threadIdx.x;
    int total = NB * Kc * Kc;
    if (idx >= total) return;
    int l = idx % Kc;
    int k = (idx / Kc) % Kc;
    int b = idx / (Kc * Kc);
    const float* pp = p + (size_t)b * Nc * Kc + k;
    const float* tp = tmp + (size_t)b * Nc * Kc + l;
    float s = 0.f;
    for (int n = 0; n < Nc; ++n) s += pp[(size_t)n * Kc] * tp[(size_t)n * Kc];
    oadj[idx] = s;
}

__device__ inline float blk_sum256(float v, float* rbuf) {
    for (int o = 32; o > 0; o >>= 1) v += __shfl_xor(v, o);
    __syncthreads();
    if ((threadIdx.x & 63) == 0) rbuf[threadIdx.x >> 6] = v;
    __syncthreads();
    return rbuf[0] + rbuf[1] + rbuf[2] + rbuf[3];
}

// one block per batch: mincut num/den, ss, ortho; accumulate into mc_out/or_out
__global__ void k_losses(const float* __restrict__ p, const float* __restrict__ dflat,
                         const float* __restrict__ oadj, float* __restrict__ mc_out,
                         float* __restrict__ or_out, int Nc, int Kc) {
    __shared__ float ss[4096];
    __shared__ float rbuf[4];
    int b = blockIdx.x, tid = threadIdx.x;
    const float* pb = p + (size_t)b * Nc * Kc;
    const float* db = dflat + (size_t)b * Nc;
    const float* ob = oadj + (size_t)b * Kc * Kc;
    float den = 0.f;
    for (int i = tid; i < Nc * Kc; i += 256) { float pv = pb[i]; den += pv * pv * db[i / Kc]; }
    for (int i = tid; i < Kc * Kc; i += 256) {
        int k = i / Kc, l = i % Kc;
        float s = 0.f;
        for (int n = 0; n < Nc; ++n) s += pb[(size_t)n * Kc + k] * pb[(size_t)n * Kc + l];
        ss[i] = s;
    }
    __syncthreads();
    float ssn2 = 0.f;
    for (int i = tid; i < Kc * Kc; i += 256) ssn2 += ss[i] * ss[i];
    float num = 0.f;
    for (int k = tid; k < Kc; k += 256) num += ob[k * Kc + k];
    float den_t = blk_sum256(den, rbuf);
    float ssn2_t = blk_sum256(ssn2, rbuf);
    float num_t = blk_sum256(num, rbuf);
    float inv = 1.0f / sqrtf(ssn2_t);
    float dk = rsqrtf((float)Kc);
    float o2 = 0.f;
    for (int i = tid; i < Kc * Kc; i += 256) {
        float v = ss[i] * inv - ((i / Kc == i % Kc) ? dk : 0.f);
        o2 += v * v;
    }
    float o2_t = blk_sum256(o2, rbuf);
    if (tid == 0) {
        atomicAdd(mc_out, -(num_t / den_t) * (1.0f / NB));
        atomicAdd(or_out, sqrtf(o2_t) * (1.0f / NB));
    }
}

// dv[b,k] = sqrt(sum_{l!=k} oadj[b,k,l]) + eps
__global__ void k_dv(const float* __restrict__ oadj, float* __restrict__ dv, int Kc) {
    int idx = blockIdx.x * 256 + threadIdx.x;
    if (idx >= NB * Kc) return;
    int k = idx % Kc, b = idx / Kc;
    const float* ob = oadj + ((size_t)b * Kc + k) * Kc;
    float s = 0.f;
    for (int l = 0; l < Kc; ++l) if (l != k) s += ob[l];
    dv[idx] = sqrtf(s) + 1e-15f;
}

// in-place: oadj[b,k,l] = (k==l) ? 0 : oadj/(dv[b,k]*dv[b,l])
__global__ void k_norm_adj(float* __restrict__ oadj, const float* __restrict__ dv, int Kc) {
    int idx = blockIdx.x * 256 + threadIdx.x;
    int total = NB * Kc * Kc;
    if (idx >= total) return;
    int l = idx % Kc;
    int k = (idx / Kc) % Kc;
    int b = idx / (Kc * Kc);
    float v = (k == l) ? 0.f : oadj[idx] / (dv[(size_t)b * Kc + k] * dv[(size_t)b * Kc + l]);
    oadj[idx] = v;
}

// agg[b,t,n,h] = sum_m adjn[b,n,m] * x[b,t,m,h]   (x layout [B,T,Nc,H])
__global__ void k_adj_x(const float* __restrict__ adjn, const float* __restrict__ x,
                        float* __restrict__ outp, int Nc) {
    int idx = blockIdx.x * 256 + threadIdx.x;
    int total = NB * TC * Nc * HC;
    if (idx >= total) return;
    int h = idx & 31;
    int rest = idx >> 5;
    int n = rest % Nc;
    int bt = rest / Nc;
    int b = bt / TC;
    const float* a = adjn + ((size_t)b * Nc + n) * Nc;
    const float* xp = x + ((size_t)bt * Nc) * HC + h;
    float s = 0.f;
    for (int m = 0; m < Nc; ++m) s += a[m] * xp[(size_t)m * HC];
    outp[idx] = s;
}

// out[r,o] = sum_h agg[r,h]*Wrel[h,o] + brel[o] + sum_h x[r,h]*Wroot[h,o]
__global__ void k_dual_linear(const float* __restrict__ agg, const float* __restrict__ xin,
                              const float* __restrict__ Wrel, const float* __restrict__ brel,
                              const float* __restrict__ Wroot, float* __restrict__ outp,
                              int R, int Oc) {
    int idx = blockIdx.x * 256 + threadIdx.x;
    if (idx >= R * Oc) return;
    int o = idx % Oc;
    int r = idx / Oc;
    const float* a = agg + (size_t)r * HC;
    const float* xp = xin + (size_t)r * HC;
    float s = brel[o];
    for (int h = 0; h < HC; ++h) s += a[h] * Wrel[h * Oc + o] + xp[h] * Wroot[h * Oc + o];
    outp[idx] = s;
}

// q[b,k,m] = sum_l p2[b,k,l] * p3[b,l,m]   (64x32 @ 32x8)
__global__ void k_p23(const float* __restrict__ p2, const float* __restrict__ p3,
                      float* __restrict__ q) {
    int idx = blockIdx.x * 256 + threadIdx.x;
    if (idx >= NB * 64 * 8) return;
    int m = idx & 7;
    int rest = idx >> 3;
    int k = rest % 64;
    int b = rest / 64;
    const float* p2p = p2 + ((size_t)b * 64 + k) * 32;
    const float* p3p = p3 + (size_t)b * 32 * 8 + m;
    float s = 0.f;
    for (int l = 0; l < 32; ++l) s += p2p[l] * p3p[(size_t)l * 8];
    q[idx] = s;
}

// aggout[b,n,m] = sum_k p1[b,n,k] * q[b,k,m]
__global__ void k_aggout(const float* __restrict__ p1, const float* __restrict__ q,
                         float* __restrict__ outp) {
    int idx = blockIdx.x * 256 + threadIdx.x;
    if (idx >= NB * 256 * 8) return;
    int m = idx & 7;
    int rest = idx >> 3;
    int n = rest & 255;
    int b = rest >> 8;
    const float* pp = p1 + ((size_t)b * 256 + n) * 64;
    const float* qp = q + (size_t)b * 512 + m;
    float s = 0.f;
    for (int k = 0; k < 64; ++k) s += pp[k] * qp[(size_t)k * 8];
    outp[idx] = s;
}

// ---------------- host launch ----------------

extern "C" void kernel_launch(void* const* d_in, const int* in_sizes, int n_in,
                              void* d_out, int out_size, void* d_ws, size_t ws_size,
                              hipStream_t stream) {
    const float* pos    = (const float*)d_in[0];
    const float* ea     = (const float*)d_in[1];
    const int*   esrc   = (const int*)d_in[2];
    const int*   edst   = (const int*)d_in[3];
    const float* W1     = (const float*)d_in[4];
    const float* b1     = (const float*)d_in[5];
    const float* Wp1    = (const float*)d_in[6];
    const float* bp1    = (const float*)d_in[7];
    const float* Wrel2  = (const float*)d_in[8];
    const float* brel2  = (const float*)d_in[9];
    const float* Wroot2 = (const float*)d_in[10];
    const float* Wp2    = (const float*)d_in[11];
    const float* bp2    = (const float*)d_in[12];
    const float* Wrel3  = (const float*)d_in[13];
    const float* brel3  = (const float*)d_in[14];
    const float* Wroot3 = (const float*)d_in[15];
    const float* Wp3    = (const float*)d_in[16];
    const float* bp3    = (const float*)d_in[17];
    const float* Wrel4  = (const float*)d_in[18];
    const float* brel4  = (const float*)d_in[19];
    const float* Wroot4 = (const float*)d_in[20];
    float* out = (float*)d_out;

    char* w = (char*)d_ws;
    float* XW  = (float*)w;                    // 33,554,432 B : xw, later adj/x1b/x2a/x2b
    float* X   = (float*)(w + 33554432);       // 33,554,432 B : y -> x (dead after L1 pool) -> TMP
    char* sp   = w + 67108864;
    float* DINV  = (float*)(sp);
    float* XM    = (float*)(sp + 65536);
    float* P1    = (float*)(sp + 2162688);
    float* X1A   = (float*)(sp + 6356992);
    float* OADJ1 = (float*)(sp + 14745600);
    float* P2    = (float*)(sp + 15794176);
    float* OADJ2 = (float*)(sp + 16318464);
    float* P3    = (float*)(sp + 16580608);
    float* X3A   = (float*)(sp + 16646144);
    float* OADJ3 = (float*)(sp + 17694720);
    float* DV    = (float*)(sp + 17711104);
    float* DFLAT = (float*)(sp + 17727488);
    float* P23   = (float*)(sp + 17793024);
    // overlays of the dead xw region:
    float* ADJ0 = XW;
    float* X1B  = (float*)(w + 16777216);
    float* X2A  = (float*)(w + 25165824);
    float* X2B  = (float*)(w + 29360128);
    float* TMP  = X;                            // valid after x is last read (L1 pool)
    float* MC   = out + 524288;                 // [mincut_total, ortho_total]

    hipMemsetAsync(X, 0, 33554432ull, stream);              // y = 0
    hipMemsetAsync(MC, 0, 8, stream);                       // loss accumulators

    // GCN conv
    k_init_deg<<<GRID(NNODES), 256, 0, stream>>>(DINV);
    k_edge_deg<<<GRID(NEDGES), 256, 0, stream>>>(edst, ea, DINV);
    k_rsqrt<<<GRID(NNODES), 256, 0, stream>>>(DINV);
    k_xw<<<GRID(NNODES * TC * HC), 256, 0, stream>>>(pos, W1, XW);
    k_scatter<<<NEDGES, 256, 0, stream>>>(esrc, edst, ea, DINV, XW, X);
    k_finalize<<<GRID(NNODES * 512), 256, 0, stream>>>(X, XW, DINV, b1);

    // dense adj (xw region now dead)
    hipMemsetAsync(ADJ0, 0, 16777216ull, stream);
    k_adj<<<GRID(NEDGES), 256, 0, stream>>>(esrc, edst, ADJ0);

    // ---- Level 1: Nc=256, Kc=64; x layout [N,T,H] => sb=131072, st=32, sn=512
    k_mean_t<<<GRID(NB * 256 * HC), 256, 0, stream>>>(X, XM, 256, 131072, 32, 512);
    k_s_softmax<<<NB * 256, 64, 0, stream>>>(XM, Wp1, bp1, P1, 64);
    k_pool_x<<<GRID(NB * TC * 64 * HC), 256, 0, stream>>>(P1, X, X1A, 256, 64, 131072, 32, 512);
    k_dflat<<<GRID(NB * 256), 256, 0, stream>>>(ADJ0, DFLAT, 256);
    k_adj_p<<<GRID(NB * 256 * 64), 256, 0, stream>>>(ADJ0, P1, TMP, 256, 64);
    k_pT_tmp<<<GRID(NB * 64 * 64), 256, 0, stream>>>(P1, TMP, OADJ1, 256, 64);
    k_losses<<<NB, 256, 0, stream>>>(P1, DFLAT, OADJ1, MC, MC + 1, 256, 64);
    k_dv<<<GRID(NB * 64), 256, 0, stream>>>(OADJ1, DV, 64);
    k_norm_adj<<<GRID(NB * 64 * 64), 256, 0, stream>>>(OADJ1, DV, 64);
    k_adj_x<<<GRID(NB * TC * 64 * HC), 256, 0, stream>>>(OADJ1, X1A, TMP, 64);
    k_dual_linear<<<GRID(NB * TC * 64 * 32), 256, 0, stream>>>(TMP, X1A, Wrel2, brel2, Wroot2, X1B, NB * TC * 64, 32);

    // ---- Level 2: Nc=64, Kc=32; x1b layout [B,T,64,32] => sb=32768, st=2048, sn=32
    k_mean_t<<<GRID(NB * 64 * HC), 256, 0, stream>>>(X1B, XM, 64, 32768, 2048, 32);
    k_s_softmax<<<NB * 64, 64, 0, stream>>>(XM, Wp2, bp2, P2, 32);
    k_pool_x<<<GRID(NB * TC * 32 * HC), 256, 0, stream>>>(P2, X1B, X2A, 64, 32, 32768, 2048, 32);
    k_dflat<<<GRID(NB * 64), 256, 0, stream>>>(OADJ1, DFLAT, 64);
    k_adj_p<<<GRID(NB * 64 * 32), 256, 0, stream>>>(OADJ1, P2, TMP, 64, 32);
    k_pT_tmp<<<GRID(NB * 32 * 32), 256, 0, stream>>>(P2, TMP, OADJ2, 64, 32);
    k_losses<<<NB, 256, 0, stream>>>(P2, DFLAT, OADJ2, MC, MC + 1, 64, 32);
    k_dv<<<GRID(NB * 32), 256, 0, stream>>>(OADJ2, DV, 32);
    k_norm_adj<<<GRID(NB * 32 * 32), 256, 0, stream>>>(OADJ2, DV, 32);
    k_adj_x<<<GRID(NB * TC * 32 * HC), 256, 0, stream>>>(OADJ2, X2A, TMP, 32);
    k_dual_linear<<<GRID(NB * TC * 32 * 32), 256, 0, stream>>>(TMP, X2A, Wrel3, brel3, Wroot3, X2B, NB * TC * 32, 32);

    // ---- Level 3: Nc=32, Kc=8; x2b layout [B,T,32,32] => sb=16384, st=1024, sn=32
    k_mean_t<<<GRID(NB * 32 * HC), 256, 0, stream>>>(X2B, XM, 32, 16384, 1024, 32);
    k_s_softmax<<<NB * 32, 64, 0, stream>>>(XM, Wp3, bp3, P3, 8);
    k_pool_x<<<GRID(NB * TC * 8 * HC), 256, 0, stream>>>(P3, X2B, X3A, 32, 8, 16384, 1024, 32);
    k_dflat<<<GRID(NB * 32), 256, 0, stream>>>(OADJ2, DFLAT, 32);
    k_adj_p<<<GRID(NB * 32 * 8), 256, 0, stream>>>(OADJ2, P3, TMP, 32, 8);
    k_pT_tmp<<<GRID(NB * 8 * 8), 256, 0, stream>>>(P3, TMP, OADJ3, 32, 8);
    k_losses<<<NB, 256, 0, stream>>>(P3, DFLAT, OADJ3, MC, MC + 1, 32, 8);
    k_dv<<<GRID(NB * 8), 256, 0, stream>>>(OADJ3, DV, 8);
    k_norm_adj<<<GRID(NB * 8 * 8), 256, 0, stream>>>(OADJ3, DV, 8);
    k_adj_x<<<GRID(NB * TC * 8 * HC), 256, 0, stream>>>(OADJ3, X3A, TMP, 8);
    k_dual_linear<<<GRID(NB * TC * 8 * 64), 256, 0, stream>>>(TMP, X3A, Wrel4, brel4, Wroot4, out, NB * TC * 8, 64);

    // ---- agg = p1 @ (p2 @ p3)
    k_p23<<<GRID(NB * 64 * 8), 256, 0, stream>>>(P2, P3, P23);
    k_aggout<<<GRID(NB * 256 * 8), 256, 0, stream>>>(P1, P23, out + 524290);
}

// Round 2
// 1199.209 us; speedup vs baseline: 1.3870x; 1.3870x over previous
//
#include <hip/hip_runtime.h>
#include <math.h>

#define NB 64
#define NMAXC 256
#define TC 16
#define HC 32
#define NNODES 16384
#define NEDGES 131072

static inline int GRID(int n) { return (n + 255) / 256; }

// ---------------- GCN conv ----------------

__global__ void k_init_deg(float* deg) {
    int i = blockIdx.x * 256 + threadIdx.x;
    if (i < NNODES) deg[i] = 1.0f;   // self-loop weight
}

__global__ void k_edge_deg(const int* __restrict__ dst, const float* __restrict__ ew,
                           float* __restrict__ deg) {
    int e = blockIdx.x * 256 + threadIdx.x;
    if (e < NEDGES) atomicAdd(&deg[dst[e]], ew[e]);
}

__global__ void k_rsqrt(float* deg) {
    int i = blockIdx.x * 256 + threadIdx.x;
    if (i < NNODES) { float d = deg[i]; deg[i] = (d > 0.f) ? rsqrtf(d) : 0.f; }
}

__global__ void k_xw(const float* __restrict__ pos, const float* __restrict__ W1,
                     float* __restrict__ xw) {
    int idx = blockIdx.x * 256 + threadIdx.x;
    if (idx >= NNODES * TC * HC) return;
    int h = idx & 31;
    int row = idx >> 5;                 // n*T + t
    const float* p = pos + (size_t)row * 3;
    xw[idx] = p[0] * W1[h] + p[1] * W1[32 + h] + p[2] * W1[64 + h];
}

// one block per edge, 256 threads, 2 features each
__global__ void k_scatter(const int* __restrict__ src, const int* __restrict__ dst,
                          const float* __restrict__ ew, const float* __restrict__ dinv,
                          const float* __restrict__ xw, float* __restrict__ y) {
    int e = blockIdx.x;
    int t = threadIdx.x;
    int s = src[e], d = dst[e];
    float coef = dinv[s] * ew[e] * dinv[d];
    const float* xs = xw + (size_t)s * 512;
    float* yd = y + (size_t)d * 512;
    atomicAdd(&yd[t], xs[t] * coef);
    atomicAdd(&yd[t + 256], xs[t + 256] * coef);
}

__global__ void k_finalize(float* __restrict__ y, const float* __restrict__ xw,
                           const float* __restrict__ dinv, const float* __restrict__ b1) {
    int idx = blockIdx.x * 256 + threadIdx.x;
    if (idx >= NNODES * 512) return;
    int h = idx & 31;
    int n = idx >> 9;
    float dv = dinv[n];
    float v = y[idx] + xw[idx] * dv * dv + b1[h];
    y[idx] = fmaxf(v, 0.0f);
}

__global__ void k_adj(const int* __restrict__ src, const int* __restrict__ dst,
                      float* __restrict__ adj) {
    int e = blockIdx.x * 256 + threadIdx.x;
    if (e >= NEDGES) return;
    int s = src[e], d = dst[e];
    int g = s >> 8;
    atomicAdd(&adj[((size_t)g << 16) + ((size_t)(s & 255) << 8) + (size_t)(d & 255)], 1.0f);
}

// ---------------- generic per-level kernels ----------------

// xm[r,h] = mean_t x[b*sb + t*st + n*sn + h],  r = b*Nc+n
__global__ void k_mean_t(const float* __restrict__ x, float* __restrict__ xm,
                         int Nc, int sb, int st, int sn) {
    int idx = blockIdx.x * 256 + threadIdx.x;
    int total = NB * Nc * HC;
    if (idx >= total) return;
    int h = idx & 31;
    int r = idx >> 5;
    int b = r / Nc, n = r % Nc;
    const float* p = x + (size_t)b * sb + (size_t)n * sn + h;
    float s = 0.f;
    for (int t = 0; t < TC; ++t) s += p[(size_t)t * st];
    xm[idx] = s * (1.0f / TC);
}

// one 64-lane wave per row: s = tanh(xm@Wp + bp), p = softmax_k(s)
__global__ void k_s_softmax(const float* __restrict__ xm, const float* __restrict__ Wp,
                            const float* __restrict__ bp, float* __restrict__ p, int Kc) {
    int r = blockIdx.x;
    int k = threadIdx.x;
    const float* xr = xm + (size_t)r * HC;
    float v = -1e30f;
    if (k < Kc) {
        float acc = bp[k];
        for (int h = 0; h < HC; ++h) acc += xr[h] * Wp[h * Kc + k];
        v = tanhf(acc);
    }
    float m = v;
    for (int o = 32; o > 0; o >>= 1) m = fmaxf(m, __shfl_xor(m, o));
    float e = (k < Kc) ? expf(v - m) : 0.f;
    float s = e;
    for (int o = 32; o > 0; o >>= 1) s += __shfl_xor(s, o);
    if (k < Kc) p[(size_t)r * Kc + k] = e / s;
}

// out[b,t,k,h] = sum_n p[(b*Nc+n)*Kc+k] * x[b*sb + t*st + n*sn + h]
__global__ void k_pool_x(const float* __restrict__ p, const float* __restrict__ x,
                         float* __restrict__ outp, int Nc, int Kc, int sb, int st, int sn) {
    int idx = blockIdx.x * 256 + threadIdx.x;
    int total = NB * TC * Kc * HC;
    if (idx >= total) return;
    int h = idx & 31;
    int rest = idx >> 5;
    int k = rest % Kc;
    int bt = rest / Kc;
    int b = bt / TC, t = bt % TC;
    const float* xp = x + (size_t)b * sb + (size_t)t * st + h;
    const float* pp = p + (size_t)b * Nc * Kc + k;
    float acc = 0.f;
    for (int n = 0; n < Nc; ++n) acc += pp[(size_t)n * Kc] * xp[(size_t)n * sn];
    outp[idx] = acc;
}

__global__ void k_dflat(const float* __restrict__ adj, float* __restrict__ dflat, int Nc) {
    int idx = blockIdx.x * 256 + threadIdx.x;
    if (idx >= NB * Nc) return;
    const float* a = adj + (size_t)idx * Nc;
    float s = 0.f;
    for (int m = 0; m < Nc; ++m) s += a[m];
    dflat[idx] = s;
}

// tmp[b,n,l] = sum_m adj[b,n,m] * p[(b*Nc+m)*Kc+l]
__global__ void k_adj_p(const float* __restrict__ adj, const float* __restrict__ p,
                        float* __restrict__ tmp, int Nc, int Kc) {
    int idx = blockIdx.x * 256 + threadIdx.x;
    int total = NB * Nc * Kc;
    if (idx >= total) return;
    int l = idx % Kc;
    int n = (idx / Kc) % Nc;
    int b = idx / (Kc * Nc);
    const float* a = adj + ((size_t)b * Nc + n) * Nc;
    const float* pp = p + (size_t)b * Nc * Kc + l;
    float s = 0.f;
    for (int m = 0; m < Nc; ++m) s += a[m] * pp[(size_t)m * Kc];
    tmp[idx] = s;
}

// oadj[b,k,l] = sum_n p[(b*Nc+n)*Kc+k] * tmp[b,n,l]
__global__ void k_pT_tmp(const float* __restrict__ p, const float* __restrict__ tmp,
                         float* __restrict__ oadj, int Nc, int Kc) {
    int idx = blockIdx.x * 256 + threadIdx.x;
    int total = NB * Kc * Kc;
    if (idx >= total) return;
    int l = idx % Kc;
    int k = (idx / Kc) % Kc;
    int b = idx / (Kc * Kc);
    const float* pp = p + (size_t)b * Nc * Kc + k;
    const float* tp = tmp + (size_t)b * Nc * Kc + l;
    float s = 0.f;
    for (int n = 0; n < Nc; ++n) s += pp[(size_t)n * Kc] * tp[(size_t)n * Kc];
    oadj[idx] = s;
}

__device__ inline float blk_sum256(float v, float* rbuf) {
    for (int o = 32; o > 0; o >>= 1) v += __shfl_xor(v, o);
    __syncthreads();
    if ((threadIdx.x & 63) == 0) rbuf[threadIdx.x >> 6] = v;
    __syncthreads();
    return rbuf[0] + rbuf[1] + rbuf[2] + rbuf[3];
}

// constexpr log2 for power-of-two sizes
template<int V> struct Log2 { static constexpr int v = 1 + Log2<V/2>::v; };
template<> struct Log2<1> { static constexpr int v = 0; };

// one block per batch, p staged in LDS chunks, 4x4 register-tiled ss GEMM.
// NCH = rows of p staged per chunk (NCH*KC <= 8192 floats = 32KB LDS).
template<int NC, int KC, int NCH>
__global__ void k_losses_t(const float* __restrict__ p, const float* __restrict__ dflat,
                           const float* __restrict__ oadj, float* __restrict__ mc_out,
                           float* __restrict__ or_out) {
    constexpr int LK = Log2<KC>::v;
    constexpr int NT = (KC / 4) * (KC / 4);      // 4x4 tiles in ss
    __shared__ __align__(16) float ps[NCH * KC];
    __shared__ __align__(16) float sss[KC * KC];
    __shared__ float rbuf[4];
    int b = blockIdx.x, tid = threadIdx.x;
    const float* pb = p + (size_t)b * NC * KC;
    const float* db = dflat + (size_t)b * NC;
    const float* ob = oadj + (size_t)b * KC * KC;

    // per-thread 4x4 tile accumulator (all compile-time indexed)
    float4 a0 = {0, 0, 0, 0}, a1 = {0, 0, 0, 0}, a2 = {0, 0, 0, 0}, a3 = {0, 0, 0, 0};
    int kt = tid >> (LK - 2);          // tile row (k0 = 4*kt)
    int lt = tid & (KC / 4 - 1);       // tile col (l0 = 4*lt)
    float den = 0.f;

    for (int n0 = 0; n0 < NC; n0 += NCH) {
        // stage chunk: NCH*KC floats, coalesced float4
        for (int i = tid; i < NCH * KC / 4; i += 256)
            ((float4*)ps)[i] = ((const float4*)(pb + (size_t)n0 * KC))[i];
        __syncthreads();
        // den partial: sum p^2 * deg (LDS reads, vectorized)
        for (int i4 = tid; i4 < NCH * KC / 4; i4 += 256) {
            float4 v = ((const float4*)ps)[i4];
            float dd = db[n0 + ((i4 * 4) >> LK)];   // 4|KC so one row per float4
            den += (v.x * v.x + v.y * v.y + v.z * v.z + v.w * v.w) * dd;
        }
        // ss 4x4 tiles
        if (tid < NT) {
            const float4* pk = (const float4*)&ps[kt * 4];
            const float4* pl = (const float4*)&ps[lt * 4];
            #pragma unroll 8
            for (int n = 0; n < NCH; ++n) {
                float4 kv = pk[n * (KC / 4)];
                float4 lv = pl[n * (KC / 4)];
                a0.x += kv.x * lv.x; a0.y += kv.x * lv.y; a0.z += kv.x * lv.z; a0.w += kv.x * lv.w;
                a1.x += kv.y * lv.x; a1.y += kv.y * lv.y; a1.z += kv.y * lv.z; a1.w += kv.y * lv.w;
                a2.x += kv.z * lv.x; a2.y += kv.z * lv.y; a2.z += kv.z * lv.z; a2.w += kv.z * lv.w;
                a3.x += kv.w * lv.x; a3.y += kv.w * lv.y; a3.z += kv.w * lv.z; a3.w += kv.w * lv.w;
            }
        }
        __syncthreads();
    }
    // write tiles to LDS ss
    if (tid < NT) {
        float* d0 = &sss[(kt * 4) * KC + lt * 4];
        *(float4*)(d0)              = a0;
        *(float4*)(d0 + KC)         = a1;
        *(float4*)(d0 + 2 * KC)     = a2;
        *(float4*)(d0 + 3 * KC)     = a3;
    }
    __syncthreads();
    // ssn2 = ||ss||_F^2 ; num = trace(oadj)
    float ssn2 = 0.f;
    for (int i = tid; i < KC * KC; i += 256) ssn2 += sss[i] * sss[i];
    float num = 0.f;
    for (int k = tid; k < KC; k += 256) num += ob[k * KC + k];
    float den_t = blk_sum256(den, rbuf);
    float ssn2_t = blk_sum256(ssn2, rbuf);
    float num_t = blk_sum256(num, rbuf);
    float inv = 1.0f / sqrtf(ssn2_t);
    float dk = rsqrtf((float)KC);
    float o2 = 0.f;
    for (int i = tid; i < KC * KC; i += 256) {
        float v = sss[i] * inv - (((i >> LK) == (i & (KC - 1))) ? dk : 0.f);
        o2 += v * v;
    }
    float o2_t = blk_sum256(o2, rbuf);
    if (tid == 0) {
        atomicAdd(mc_out, -(num_t / den_t) * (1.0f / NB));
        atomicAdd(or_out, sqrtf(o2_t) * (1.0f / NB));
    }
}

// dv[b,k] = sqrt(sum_{l!=k} oadj[b,k,l]) + eps
__global__ void k_dv(const float* __restrict__ oadj, float* __restrict__ dv, int Kc) {
    int idx = blockIdx.x * 256 + threadIdx.x;
    if (idx >= NB * Kc) return;
    int k = idx % Kc, b = idx / Kc;
    const float* ob = oadj + ((size_t)b * Kc + k) * Kc;
    float s = 0.f;
    for (int l = 0; l < Kc; ++l) if (l != k) s += ob[l];
    dv[idx] = sqrtf(s) + 1e-15f;
}

// in-place: oadj[b,k,l] = (k==l) ? 0 : oadj/(dv[b,k]*dv[b,l])
__global__ void k_norm_adj(float* __restrict__ oadj, const float* __restrict__ dv, int Kc) {
    int idx = blockIdx.x * 256 + threadIdx.x;
    int total = NB * Kc * Kc;
    if (idx >= total) return;
    int l = idx % Kc;
    int k = (idx / Kc) % Kc;
    int b = idx / (Kc * Kc);
    float v = (k == l) ? 0.f : oadj[idx] / (dv[(size_t)b * Kc + k] * dv[(size_t)b * Kc + l]);
    oadj[idx] = v;
}

// agg[b,t,n,h] = sum_m adjn[b,n,m] * x[b,t,m,h]   (x layout [B,T,Nc,H])
__global__ void k_adj_x(const float* __restrict__ adjn, const float* __restrict__ x,
                        float* __restrict__ outp, int Nc) {
    int idx = blockIdx.x * 256 + threadIdx.x;
    int total = NB * TC * Nc * HC;
    if (idx >= total) return;
    int h = idx & 31;
    int rest = idx >> 5;
    int n = rest % Nc;
    int bt = rest / Nc;
    int b = bt / TC;
    const float* a = adjn + ((size_t)b * Nc + n) * Nc;
    const float* xp = x + ((size_t)bt * Nc) * HC + h;
    float s = 0.f;
    for (int m = 0; m < Nc; ++m) s += a[m] * xp[(size_t)m * HC];
    outp[idx] = s;
}

// out[r,o] = sum_h agg[r,h]*Wrel[h,o] + brel[o] + sum_h x[r,h]*Wroot[h,o]
__global__ void k_dual_linear(const float* __restrict__ agg, const float* __restrict__ xin,
                              const float* __restrict__ Wrel, const float* __restrict__ brel,
                              const float* __restrict__ Wroot, float* __restrict__ outp,
                              int R, int Oc) {
    int idx = blockIdx.x * 256 + threadIdx.x;
    if (idx >= R * Oc) return;
    int o = idx % Oc;
    int r = idx / Oc;
    const float* a = agg + (size_t)r * HC;
    const float* xp = xin + (size_t)r * HC;
    float s = brel[o];
    for (int h = 0; h < HC; ++h) s += a[h] * Wrel[h * Oc + o] + xp[h] * Wroot[h * Oc + o];
    outp[idx] = s;
}

// q[b,k,m] = sum_l p2[b,k,l] * p3[b,l,m]   (64x32 @ 32x8)
__global__ void k_p23(const float* __restrict__ p2, const float* __restrict__ p3,
                      float* __restrict__ q) {
    int idx = blockIdx.x * 256 + threadIdx.x;
    if (idx >= NB * 64 * 8) return;
    int m = idx & 7;
    int rest = idx >> 3;
    int k = rest % 64;
    int b = rest / 64;
    const float* p2p = p2 + ((size_t)b * 64 + k) * 32;
    const float* p3p = p3 + (size_t)b * 32 * 8 + m;
    float s = 0.f;
    for (int l = 0; l < 32; ++l) s += p2p[l] * p3p[(size_t)l * 8];
    q[idx] = s;
}

// aggout[b,n,m] = sum_k p1[b,n,k] * q[b,k,m]
__global__ void k_aggout(const float* __restrict__ p1, const float* __restrict__ q,
                         float* __restrict__ outp) {
    int idx = blockIdx.x * 256 + threadIdx.x;
    if (idx >= NB * 256 * 8) return;
    int m = idx & 7;
    int rest = idx >> 3;
    int n = rest & 255;
    int b = rest >> 8;
    const float* pp = p1 + ((size_t)b * 256 + n) * 64;
    const float* qp = q + (size_t)b * 512 + m;
    float s = 0.f;
    for (int k = 0; k < 64; ++k) s += pp[k] * qp[(size_t)k * 8];
    outp[idx] = s;
}

// ---------------- host launch ----------------

extern "C" void kernel_launch(void* const* d_in, const int* in_sizes, int n_in,
                              void* d_out, int out_size, void* d_ws, size_t ws_size,
                              hipStream_t stream) {
    const float* pos    = (const float*)d_in[0];
    const float* ea     = (const float*)d_in[1];
    const int*   esrc   = (const int*)d_in[2];
    const int*   edst   = (const int*)d_in[3];
    const float* W1     = (const float*)d_in[4];
    const float* b1     = (const float*)d_in[5];
    const float* Wp1    = (const float*)d_in[6];
    const float* bp1    = (const float*)d_in[7];
    const float* Wrel2  = (const float*)d_in[8];
    const float* brel2  = (const float*)d_in[9];
    const float* Wroot2 = (const float*)d_in[10];
    const float* Wp2    = (const float*)d_in[11];
    const float* bp2    = (const float*)d_in[12];
    const float* Wrel3  = (const float*)d_in[13];
    const float* brel3  = (const float*)d_in[14];
    const float* Wroot3 = (const float*)d_in[15];
    const float* Wp3    = (const float*)d_in[16];
    const float* bp3    = (const float*)d_in[17];
    const float* Wrel4  = (const float*)d_in[18];
    const float* brel4  = (const float*)d_in[19];
    const float* Wroot4 = (const float*)d_in[20];
    float* out = (float*)d_out;

    char* w = (char*)d_ws;
    float* XW  = (float*)w;                    // 33,554,432 B : xw, later adj/x1b/x2a/x2b
    float* X   = (float*)(w + 33554432);       // 33,554,432 B : y -> x (dead after L1 pool) -> TMP
    char* sp   = w + 67108864;
    float* DINV  = (float*)(sp);
    float* XM    = (float*)(sp + 65536);
    float* P1    = (float*)(sp + 2162688);
    float* X1A   = (float*)(sp + 6356992);
    float* OADJ1 = (float*)(sp + 14745600);
    float* P2    = (float*)(sp + 15794176);
    float* OADJ2 = (float*)(sp + 16318464);
    float* P3    = (float*)(sp + 16580608);
    float* X3A   = (float*)(sp + 16646144);
    float* OADJ3 = (float*)(sp + 17694720);
    float* DV    = (float*)(sp + 17711104);
    float* DFLAT = (float*)(sp + 17727488);
    float* P23   = (float*)(sp + 17793024);
    // overlays of the dead xw region:
    float* ADJ0 = XW;
    float* X1B  = (float*)(w + 16777216);
    float* X2A  = (float*)(w + 25165824);
    float* X2B  = (float*)(w + 29360128);
    float* TMP  = X;                            // valid after x is last read (L1 pool)
    float* MC   = out + 524288;                 // [mincut_total, ortho_total]

    hipMemsetAsync(X, 0, 33554432ull, stream);              // y = 0
    hipMemsetAsync(MC, 0, 8, stream);                       // loss accumulators

    // GCN conv
    k_init_deg<<<GRID(NNODES), 256, 0, stream>>>(DINV);
    k_edge_deg<<<GRID(NEDGES), 256, 0, stream>>>(edst, ea, DINV);
    k_rsqrt<<<GRID(NNODES), 256, 0, stream>>>(DINV);
    k_xw<<<GRID(NNODES * TC * HC), 256, 0, stream>>>(pos, W1, XW);
    k_scatter<<<NEDGES, 256, 0, stream>>>(esrc, edst, ea, DINV, XW, X);
    k_finalize<<<GRID(NNODES * 512), 256, 0, stream>>>(X, XW, DINV, b1);

    // dense adj (xw region now dead)
    hipMemsetAsync(ADJ0, 0, 16777216ull, stream);
    k_adj<<<GRID(NEDGES), 256, 0, stream>>>(esrc, edst, ADJ0);

    // ---- Level 1: Nc=256, Kc=64; x layout [N,T,H] => sb=131072, st=32, sn=512
    k_mean_t<<<GRID(NB * 256 * HC), 256, 0, stream>>>(X, XM, 256, 131072, 32, 512);
    k_s_softmax<<<NB * 256, 64, 0, stream>>>(XM, Wp1, bp1, P1, 64);
    k_pool_x<<<GRID(NB * TC * 64 * HC), 256, 0, stream>>>(P1, X, X1A, 256, 64, 131072, 32, 512);
    k_dflat<<<GRID(NB * 256), 256, 0, stream>>>(ADJ0, DFLAT, 256);
    k_adj_p<<<GRID(NB * 256 * 64), 256, 0, stream>>>(ADJ0, P1, TMP, 256, 64);
    k_pT_tmp<<<GRID(NB * 64 * 64), 256, 0, stream>>>(P1, TMP, OADJ1, 256, 64);
    k_losses_t<256, 64, 128><<<NB, 256, 0, stream>>>(P1, DFLAT, OADJ1, MC, MC + 1);
    k_dv<<<GRID(NB * 64), 256, 0, stream>>>(OADJ1, DV, 64);
    k_norm_adj<<<GRID(NB * 64 * 64), 256, 0, stream>>>(OADJ1, DV, 64);
    k_adj_x<<<GRID(NB * TC * 64 * HC), 256, 0, stream>>>(OADJ1, X1A, TMP, 64);
    k_dual_linear<<<GRID(NB * TC * 64 * 32), 256, 0, stream>>>(TMP, X1A, Wrel2, brel2, Wroot2, X1B, NB * TC * 64, 32);

    // ---- Level 2: Nc=64, Kc=32; x1b layout [B,T,64,32] => sb=32768, st=2048, sn=32
    k_mean_t<<<GRID(NB * 64 * HC), 256, 0, stream>>>(X1B, XM, 64, 32768, 2048, 32);
    k_s_softmax<<<NB * 64, 64, 0, stream>>>(XM, Wp2, bp2, P2, 32);
    k_pool_x<<<GRID(NB * TC * 32 * HC), 256, 0, stream>>>(P2, X1B, X2A, 64, 32, 32768, 2048, 32);
    k_dflat<<<GRID(NB * 64), 256, 0, stream>>>(OADJ1, DFLAT, 64);
    k_adj_p<<<GRID(NB * 64 * 32), 256, 0, stream>>>(OADJ1, P2, TMP, 64, 32);
    k_pT_tmp<<<GRID(NB * 32 * 32), 256, 0, stream>>>(P2, TMP, OADJ2, 64, 32);
    k_losses_t<64, 32, 64><<<NB, 256, 0, stream>>>(P2, DFLAT, OADJ2, MC, MC + 1);
    k_dv<<<GRID(NB * 32), 256, 0, stream>>>(OADJ2, DV, 32);
    k_norm_adj<<<GRID(NB * 32 * 32), 256, 0, stream>>>(OADJ2, DV, 32);
    k_adj_x<<<GRID(NB * TC * 32 * HC), 256, 0, stream>>>(OADJ2, X2A, TMP, 32);
    k_dual_linear<<<GRID(NB * TC * 32 * 32), 256, 0, stream>>>(TMP, X2A, Wrel3, brel3, Wroot3, X2B, NB * TC * 32, 32);

    // ---- Level 3: Nc=32, Kc=8; x2b layout [B,T,32,32] => sb=16384, st=1024, sn=32
    k_mean_t<<<GRID(NB * 32 * HC), 256, 0, stream>>>(X2B, XM, 32, 16384, 1024, 32);
    k_s_softmax<<<NB * 32, 64, 0, stream>>>(XM, Wp3, bp3, P3, 8);
    k_pool_x<<<GRID(NB * TC * 8 * HC), 256, 0, stream>>>(P3, X2B, X3A, 32, 8, 16384, 1024, 32);
    k_dflat<<<GRID(NB * 32), 256, 0, stream>>>(OADJ2, DFLAT, 32);
    k_adj_p<<<GRID(NB * 32 * 8), 256, 0, stream>>>(OADJ2, P3, TMP, 32, 8);
    k_pT_tmp<<<GRID(NB * 8 * 8), 256, 0, stream>>>(P3, TMP, OADJ3, 32, 8);
    k_losses_t<32, 8, 32><<<NB, 256, 0, stream>>>(P3, DFLAT, OADJ3, MC, MC + 1);
    k_dv<<<GRID(NB * 8), 256, 0, stream>>>(OADJ3, DV, 8);
    k_norm_adj<<<GRID(NB * 8 * 8), 256, 0, stream>>>(OADJ3, DV, 8);
    k_adj_x<<<GRID(NB * TC * 8 * HC), 256, 0, stream>>>(OADJ3, X3A, TMP, 8);
    k_dual_linear<<<GRID(NB * TC * 8 * 64), 256, 0, stream>>>(TMP, X3A, Wrel4, brel4, Wroot4, out, NB * TC * 8, 64);

    // ---- agg = p1 @ (p2 @ p3)
    k_p23<<<GRID(NB * 64 * 8), 256, 0, stream>>>(P2, P3, P23);
    k_aggout<<<GRID(NB * 256 * 8), 256, 0, stream>>>(P1, P23, out + 524290);
}

// Round 3
// 523.989 us; speedup vs baseline: 3.1743x; 2.2886x over previous
//
#include <hip/hip_runtime.h>
#include <math.h>

#define NB 64
#define TC 16
#define HC 32
#define NNODES 16384
#define NEDGES 131072
#define EPSV 1e-15f

static inline int GRID(int n) { return (n + 255) / 256; }

template<int V> struct Log2 { static constexpr int v = 1 + Log2<V/2>::v; };
template<> struct Log2<1> { static constexpr int v = 0; };

// ---------------- GCN conv front-end ----------------

__global__ void k_init_deg(float* deg) {
    int i = blockIdx.x * 256 + threadIdx.x;
    if (i < NNODES) deg[i] = 1.0f;   // self-loop weight
}

__global__ void k_edge_deg(const int* __restrict__ dst, const float* __restrict__ ew,
                           float* __restrict__ deg) {
    int e = blockIdx.x * 256 + threadIdx.x;
    if (e < NEDGES) atomicAdd(&deg[dst[e]], ew[e]);
}

__global__ void k_rsqrt(float* deg) {
    int i = blockIdx.x * 256 + threadIdx.x;
    if (i < NNODES) { float d = deg[i]; deg[i] = (d > 0.f) ? rsqrtf(d) : 0.f; }
}

__global__ void k_xw(const float* __restrict__ pos, const float* __restrict__ W1,
                     float* __restrict__ xw) {
    int idx = blockIdx.x * 256 + threadIdx.x;
    if (idx >= NNODES * TC * HC) return;
    int h = idx & 31;
    int row = idx >> 5;                 // n*T + t
    const float* p = pos + (size_t)row * 3;
    xw[idx] = p[0] * W1[h] + p[1] * W1[32 + h] + p[2] * W1[64 + h];
}

// one block per edge, 256 threads, 2 features each
__global__ void k_scatter(const int* __restrict__ src, const int* __restrict__ dst,
                          const float* __restrict__ ew, const float* __restrict__ dinv,
                          const float* __restrict__ xw, float* __restrict__ y) {
    int e = blockIdx.x;
    int t = threadIdx.x;
    int s = src[e], d = dst[e];
    float coef = dinv[s] * ew[e] * dinv[d];
    const float* xs = xw + (size_t)s * 512;
    float* yd = y + (size_t)d * 512;
    atomicAdd(&yd[t], xs[t] * coef);
    atomicAdd(&yd[t + 256], xs[t + 256] * coef);
}

__global__ void k_finalize(float* __restrict__ y, const float* __restrict__ xw,
                           const float* __restrict__ dinv, const float* __restrict__ b1) {
    int idx = blockIdx.x * 256 + threadIdx.x;
    if (idx >= NNODES * 512) return;
    int h = idx & 31;
    int n = idx >> 9;
    float dv = dinv[n];
    float v = y[idx] + xw[idx] * dv * dv + b1[h];
    y[idx] = fmaxf(v, 0.0f);
}

__global__ void k_adj(const int* __restrict__ src, const int* __restrict__ dst,
                      float* __restrict__ adj) {
    int e = blockIdx.x * 256 + threadIdx.x;
    if (e >= NEDGES) return;
    int s = src[e], d = dst[e];
    int g = s >> 8;
    atomicAdd(&adj[((size_t)g << 16) + ((size_t)(s & 255) << 8) + (size_t)(d & 255)], 1.0f);
}

// ---------------- level kernels ----------------

// xm[r,h] = mean_t x[b*sb + t*st + n*sn + h],  r = b*Nc+n
__global__ void k_mean_t(const float* __restrict__ x, float* __restrict__ xm,
                         int Nc, int sb, int st, int sn) {
    int idx = blockIdx.x * 256 + threadIdx.x;
    int total = NB * Nc * HC;
    if (idx >= total) return;
    int h = idx & 31;
    int r = idx >> 5;
    int b = r / Nc, n = r % Nc;
    const float* p = x + (size_t)b * sb + (size_t)n * sn + h;
    float s = 0.f;
    for (int t = 0; t < TC; ++t) s += p[(size_t)t * st];
    xm[idx] = s * (1.0f / TC);
}

// one 64-lane wave per row: s = tanh(xm@Wp + bp), p = softmax_k(s)
__global__ void k_s_softmax(const float* __restrict__ xm, const float* __restrict__ Wp,
                            const float* __restrict__ bp, float* __restrict__ p, int Kc) {
    int r = blockIdx.x;
    int k = threadIdx.x;
    const float* xr = xm + (size_t)r * HC;
    float v = -1e30f;
    if (k < Kc) {
        float acc = bp[k];
        for (int h = 0; h < HC; ++h) acc += xr[h] * Wp[h * Kc + k];
        v = tanhf(acc);
    }
    float m = v;
    for (int o = 32; o > 0; o >>= 1) m = fmaxf(m, __shfl_xor(m, o));
    float e = (k < Kc) ? expf(v - m) : 0.f;
    float s = e;
    for (int o = 32; o > 0; o >>= 1) s += __shfl_xor(s, o);
    if (k < Kc) p[(size_t)r * Kc + k] = e / s;
}

// out[b,t,k,h] = sum_n p[(b*NC+n)*KC+k] * x[b*SB + t*STT + n*STN + h]
// block per (b,t); x tile + p chunk staged in LDS; thread owns (h, KPT k's)
template<int NC, int KC, int NCH, int SB, int STT, int STN>
__global__ void k_pool_t(const float* __restrict__ p, const float* __restrict__ x,
                         float* __restrict__ outp) {
    constexpr int KPT = KC / 8;
    __shared__ __align__(16) float xs[NCH * HC];
    __shared__ __align__(16) float ps[NCH * KC];
    int bt = blockIdx.x;
    int b = bt >> 4, t = bt & 15;
    int tid = threadIdx.x;
    int h = tid & 31;
    int k0 = (tid >> 5) * KPT;
    float acc[KPT];
#pragma unroll
    for (int j = 0; j < KPT; ++j) acc[j] = 0.f;
    const float* xbase = x + (size_t)b * SB + (size_t)t * STT;
    const float* pbase = p + (size_t)b * NC * KC;
    for (int n0 = 0; n0 < NC; n0 += NCH) {
        for (int i = tid; i < NCH * 8; i += 256) {
            int n = i >> 3, q = i & 7;
            ((float4*)xs)[i] = ((const float4*)(xbase + (size_t)(n0 + n) * STN))[q];
        }
        for (int i = tid; i < NCH * KC / 4; i += 256)
            ((float4*)ps)[i] = ((const float4*)(pbase + (size_t)n0 * KC))[i];
        __syncthreads();
#pragma unroll 4
        for (int n = 0; n < NCH; ++n) {
            float xv = xs[n * HC + h];
#pragma unroll
            for (int j = 0; j < KPT; ++j) acc[j] += ps[n * KC + k0 + j] * xv;
        }
        __syncthreads();
    }
#pragma unroll
    for (int j = 0; j < KPT; ++j)
        outp[((size_t)bt * KC + k0 + j) * HC + h] = acc[j];
}

__global__ void k_dflat(const float* __restrict__ adj, float* __restrict__ dflat, int Nc) {
    int idx = blockIdx.x * 256 + threadIdx.x;
    if (idx >= NB * Nc) return;
    const float* a = adj + (size_t)idx * Nc;
    float s = 0.f;
    for (int m = 0; m < Nc; ++m) s += a[m];
    dflat[idx] = s;
}

// tmp[b,n,l] = sum_m adj[b,n,m]*p[b,m,l]; block per (b, 32-n tile), LDS staged
template<int NC, int KC, int MCH>
__global__ void k_adjp_t(const float* __restrict__ adj, const float* __restrict__ p,
                         float* __restrict__ tmp) {
    constexpr int LPT = KC / 8;
    constexpr int MROW = MCH + 4;        // +4 pad: (MROW&31)==4 spreads n-groups over banks
    constexpr int MQ = MCH / 4;
    constexpr int NBK = NC / 32;
    __shared__ __align__(16) float ps[MCH * KC];
    __shared__ __align__(16) float as_[32 * MROW];
    int b = blockIdx.x / NBK;
    int nt0 = (blockIdx.x % NBK) * 32;
    int tid = threadIdx.x;
    int n = tid >> 3;
    int l0 = (tid & 7) * LPT;
    float acc[LPT];
#pragma unroll
    for (int j = 0; j < LPT; ++j) acc[j] = 0.f;
    for (int m0 = 0; m0 < NC; m0 += MCH) {
        for (int i = tid; i < MCH * KC / 4; i += 256)
            ((float4*)ps)[i] = ((const float4*)(p + ((size_t)b * NC + m0) * KC))[i];
        for (int i = tid; i < 32 * MQ; i += 256) {
            int r = i / MQ, q = i % MQ;
            ((float4*)(as_ + r * MROW))[q] =
                ((const float4*)(adj + ((size_t)b * NC + nt0 + r) * NC + m0))[q];
        }
        __syncthreads();
#pragma unroll 4
        for (int m = 0; m < MCH; ++m) {
            float av = as_[n * MROW + m];
#pragma unroll
            for (int j = 0; j < LPT; ++j) acc[j] += av * ps[m * KC + l0 + j];
        }
        __syncthreads();
    }
#pragma unroll
    for (int j = 0; j < LPT; ++j)
        tmp[((size_t)b * NC + nt0 + n) * KC + l0 + j] = acc[j];
}

__device__ inline float blk_sum256(float v, float* rbuf) {
    for (int o = 32; o > 0; o >>= 1) v += __shfl_xor(v, o);
    __syncthreads();
    if ((threadIdx.x & 63) == 0) rbuf[threadIdx.x >> 6] = v;
    __syncthreads();
    return rbuf[0] + rbuf[1] + rbuf[2] + rbuf[3];
}

// Fused: oadj = p^T tmp (out_adj), ss = p^T p, mincut/ortho losses,
// zero-diag + degree-normalize oadj -> oadj_out, optional next-level dflat.
template<int NC, int KC, int NCH, bool DFN>
__global__ void k_post_t(const float* __restrict__ p, const float* __restrict__ tmp,
                         const float* __restrict__ dflat, float* __restrict__ oadj_out,
                         float* __restrict__ dfn_out, float* __restrict__ mc_out,
                         float* __restrict__ or_out) {
    constexpr int LK = Log2<KC>::v;
    constexpr int KCP = KC + 1;          // pad for conflict-free row walks
    constexpr int TW = KC / 4;
    constexpr int NT = TW * TW;
    __shared__ __align__(16) float ps[NCH * KC];
    __shared__ __align__(16) float ts[NCH * KC];
    __shared__ float sss[KC * KCP];
    __shared__ float oss[KC * KCP];
    __shared__ float dvv[KC];
    __shared__ float rbuf[4];
    int b = blockIdx.x, tid = threadIdx.x;
    const float* pb = p + (size_t)b * NC * KC;
    const float* tb = tmp + (size_t)b * NC * KC;
    const float* db = dflat + (size_t)b * NC;
    float sa[4][4], oa[4][4];
#pragma unroll
    for (int r = 0; r < 4; ++r)
#pragma unroll
        for (int c = 0; c < 4; ++c) { sa[r][c] = 0.f; oa[r][c] = 0.f; }
    int kt = (tid < NT) ? tid / TW : 0;
    int lt = (tid < NT) ? tid % TW : 0;
    float den = 0.f;
    for (int n0 = 0; n0 < NC; n0 += NCH) {
        for (int i = tid; i < NCH * KC / 4; i += 256) {
            ((float4*)ps)[i] = ((const float4*)(pb + (size_t)n0 * KC))[i];
            ((float4*)ts)[i] = ((const float4*)(tb + (size_t)n0 * KC))[i];
        }
        __syncthreads();
        for (int i4 = tid; i4 < NCH * KC / 4; i4 += 256) {
            float4 v = ((const float4*)ps)[i4];
            float dd = db[n0 + ((i4 * 4) >> LK)];
            den += (v.x * v.x + v.y * v.y + v.z * v.z + v.w * v.w) * dd;
        }
        if (tid < NT) {
#pragma unroll 4
            for (int nn = 0; nn < NCH; ++nn) {
                float4 kv4 = *(const float4*)&ps[nn * KC + kt * 4];
                float4 lv4 = *(const float4*)&ps[nn * KC + lt * 4];
                float4 tv4 = *(const float4*)&ts[nn * KC + lt * 4];
                float kv[4] = {kv4.x, kv4.y, kv4.z, kv4.w};
                float lv[4] = {lv4.x, lv4.y, lv4.z, lv4.w};
                float tv[4] = {tv4.x, tv4.y, tv4.z, tv4.w};
#pragma unroll
                for (int r = 0; r < 4; ++r)
#pragma unroll
                    for (int c = 0; c < 4; ++c) {
                        sa[r][c] += kv[r] * lv[c];
                        oa[r][c] += kv[r] * tv[c];
                    }
            }
        }
        __syncthreads();
    }
    if (tid < NT) {
#pragma unroll
        for (int r = 0; r < 4; ++r)
#pragma unroll
            for (int c = 0; c < 4; ++c) {
                sss[(kt * 4 + r) * KCP + lt * 4 + c] = sa[r][c];
                oss[(kt * 4 + r) * KCP + lt * 4 + c] = oa[r][c];
            }
    }
    __syncthreads();
    float ssn2 = 0.f;
    for (int i = tid; i < KC * KC; i += 256) {
        int k = i >> LK, l = i & (KC - 1);
        float v = sss[k * KCP + l];
        ssn2 += v * v;
    }
    float num = 0.f;
    for (int k = tid; k < KC; k += 256) num += oss[k * KCP + k];
    float den_t = blk_sum256(den, rbuf);
    float ssn2_t = blk_sum256(ssn2, rbuf);
    float num_t = blk_sum256(num, rbuf);
    float inv = 1.0f / sqrtf(ssn2_t);
    float dk = rsqrtf((float)KC);
    float o2 = 0.f;
    for (int i = tid; i < KC * KC; i += 256) {
        int k = i >> LK, l = i & (KC - 1);
        float v = sss[k * KCP + l] * inv - ((k == l) ? dk : 0.f);
        o2 += v * v;
    }
    float o2_t = blk_sum256(o2, rbuf);
    if (tid == 0) {
        atomicAdd(mc_out, -(num_t / den_t) * (1.0f / NB));
        atomicAdd(or_out, sqrtf(o2_t) * (1.0f / NB));
    }
    if (tid < KC) {
        float rs = 0.f;
        for (int l = 0; l < KC; ++l) rs += oss[tid * KCP + l];
        rs -= oss[tid * KCP + tid];
        dvv[tid] = sqrtf(rs) + EPSV;
    }
    __syncthreads();
    for (int i = tid; i < KC * KC; i += 256) {
        int k = i >> LK, l = i & (KC - 1);
        float v = (k == l) ? 0.f : oss[k * KCP + l] / (dvv[k] * dvv[l]);
        oadj_out[(size_t)b * KC * KC + i] = v;
    }
    if (DFN && tid < KC) {
        float s = 0.f;
        for (int l = 0; l < KC; ++l)
            if (l != tid) s += oss[tid * KCP + l] / (dvv[tid] * dvv[l]);
        dfn_out[(size_t)b * KC + tid] = s;
    }
}

// Fused dense_graph_conv per (b,t): out = (adjn@x)@Wrel + brel + x@Wroot
template<int NC2, int OC>
__global__ void k_graphconv_t(const float* __restrict__ adjn, const float* __restrict__ x,
                              const float* __restrict__ Wrel, const float* __restrict__ brel,
                              const float* __restrict__ Wroot, float* __restrict__ outp) {
    constexpr int EL1 = NC2 * HC / 256;
    constexpr int EL2 = NC2 * OC / 256;
    constexpr int LOC = Log2<OC>::v;
    __shared__ __align__(16) float xs[NC2 * HC];
    __shared__ __align__(16) float as_[NC2 * NC2];
    __shared__ float c1[NC2 * HC];
    int bt = blockIdx.x;
    int b = bt >> 4;
    int tid = threadIdx.x;
    for (int i = tid; i < NC2 * HC / 4; i += 256)
        ((float4*)xs)[i] = ((const float4*)(x + (size_t)bt * NC2 * HC))[i];
    for (int i = tid; i < NC2 * NC2 / 4; i += 256)
        ((float4*)as_)[i] = ((const float4*)(adjn + (size_t)b * NC2 * NC2))[i];
    __syncthreads();
#pragma unroll
    for (int e = 0; e < EL1; ++e) {
        int idx = tid + e * 256;
        int hh = idx & 31, n = idx >> 5;
        float acc = 0.f;
#pragma unroll 8
        for (int m = 0; m < NC2; ++m) acc += as_[n * NC2 + m] * xs[m * HC + hh];
        c1[idx] = acc;
    }
    __syncthreads();
#pragma unroll
    for (int e = 0; e < EL2; ++e) {
        int idx = tid + e * 256;
        int o = idx & (OC - 1), n = idx >> LOC;
        float acc = brel[o];
#pragma unroll 8
        for (int hh = 0; hh < HC; ++hh)
            acc += c1[n * HC + hh] * Wrel[hh * OC + o] + xs[n * HC + hh] * Wroot[hh * OC + o];
        outp[(size_t)bt * NC2 * OC + idx] = acc;
    }
}

// q[b,k,m] = sum_l p2[b,k,l] * p3[b,l,m]   (64x32 @ 32x8)
__global__ void k_p23(const float* __restrict__ p2, const float* __restrict__ p3,
                      float* __restrict__ q) {
    int idx = blockIdx.x * 256 + threadIdx.x;
    if (idx >= NB * 64 * 8) return;
    int m = idx & 7;
    int rest = idx >> 3;
    int k = rest % 64;
    int b = rest / 64;
    const float* p2p = p2 + ((size_t)b * 64 + k) * 32;
    const float* p3p = p3 + (size_t)b * 32 * 8 + m;
    float s = 0.f;
    for (int l = 0; l < 32; ++l) s += p2p[l] * p3p[(size_t)l * 8];
    q[idx] = s;
}

// aggout[b,n,m] = sum_k p1[b,n,k] * q[b,k,m]
__global__ void k_aggout(const float* __restrict__ p1, const float* __restrict__ q,
                         float* __restrict__ outp) {
    int idx = blockIdx.x * 256 + threadIdx.x;
    if (idx >= NB * 256 * 8) return;
    int m = idx & 7;
    int rest = idx >> 3;
    int n = rest & 255;
    int b = rest >> 8;
    const float* pp = p1 + ((size_t)b * 256 + n) * 64;
    const float* qp = q + (size_t)b * 512 + m;
    float s = 0.f;
    for (int k = 0; k < 64; ++k) s += pp[k] * qp[(size_t)k * 8];
    outp[idx] = s;
}

// ---------------- host launch ----------------

extern "C" void kernel_launch(void* const* d_in, const int* in_sizes, int n_in,
                              void* d_out, int out_size, void* d_ws, size_t ws_size,
                              hipStream_t stream) {
    const float* pos    = (const float*)d_in[0];
    const float* ea     = (const float*)d_in[1];
    const int*   esrc   = (const int*)d_in[2];
    const int*   edst   = (const int*)d_in[3];
    const float* W1     = (const float*)d_in[4];
    const float* b1     = (const float*)d_in[5];
    const float* Wp1    = (const float*)d_in[6];
    const float* bp1    = (const float*)d_in[7];
    const float* Wrel2  = (const float*)d_in[8];
    const float* brel2  = (const float*)d_in[9];
    const float* Wroot2 = (const float*)d_in[10];
    const float* Wp2    = (const float*)d_in[11];
    const float* bp2    = (const float*)d_in[12];
    const float* Wrel3  = (const float*)d_in[13];
    const float* brel3  = (const float*)d_in[14];
    const float* Wroot3 = (const float*)d_in[15];
    const float* Wp3    = (const float*)d_in[16];
    const float* bp3    = (const float*)d_in[17];
    const float* Wrel4  = (const float*)d_in[18];
    const float* brel4  = (const float*)d_in[19];
    const float* Wroot4 = (const float*)d_in[20];
    float* out = (float*)d_out;

    char* w = (char*)d_ws;
    float* XW  = (float*)w;                    // 33.5 MB : xw, later adj/x1b/x2a/x2b
    float* X   = (float*)(w + 33554432);       // 33.5 MB : y -> x -> TMP
    char* sp   = w + 67108864;
    float* DINV   = (float*)(sp);
    float* XM     = (float*)(sp + 65536);          // 2 MB region (L1 use)
    float* DFLAT2 = (float*)(sp + 1114112);        // dead XM tail after L1 softmax
    float* DFLAT3 = (float*)(sp + 1130496);
    float* P1     = (float*)(sp + 2162688);
    float* X1A    = (float*)(sp + 6356992);
    float* OADJ1  = (float*)(sp + 14745600);
    float* P2     = (float*)(sp + 15794176);
    float* OADJ2  = (float*)(sp + 16318464);
    float* P3     = (float*)(sp + 16580608);
    float* X3A    = (float*)(sp + 16646144);
    float* OADJ3  = (float*)(sp + 17694720);
    float* DFLAT  = (float*)(sp + 17727488);
    float* P23    = (float*)(sp + 17793024);
    // overlays of the dead xw region:
    float* ADJ0 = XW;
    float* X1B  = (float*)(w + 16777216);
    float* X2A  = (float*)(w + 25165824);
    float* X2B  = (float*)(w + 29360128);
    float* TMP  = X;                            // valid after x's last read (L1 pool)
    float* MC   = out + 524288;                 // [mincut_total, ortho_total]

    hipMemsetAsync(X, 0, 33554432ull, stream);              // y = 0
    hipMemsetAsync(MC, 0, 8, stream);                       // loss accumulators

    // GCN conv
    k_init_deg<<<GRID(NNODES), 256, 0, stream>>>(DINV);
    k_edge_deg<<<GRID(NEDGES), 256, 0, stream>>>(edst, ea, DINV);
    k_rsqrt<<<GRID(NNODES), 256, 0, stream>>>(DINV);
    k_xw<<<GRID(NNODES * TC * HC), 256, 0, stream>>>(pos, W1, XW);
    k_scatter<<<NEDGES, 256, 0, stream>>>(esrc, edst, ea, DINV, XW, X);
    k_finalize<<<GRID(NNODES * 512), 256, 0, stream>>>(X, XW, DINV, b1);

    // dense adj (xw region now dead)
    hipMemsetAsync(ADJ0, 0, 16777216ull, stream);
    k_adj<<<GRID(NEDGES), 256, 0, stream>>>(esrc, edst, ADJ0);

    // ---- Level 1: Nc=256, Kc=64; x layout [N,T,H]: sb=131072, st=32, sn=512
    k_mean_t<<<GRID(NB * 256 * HC), 256, 0, stream>>>(X, XM, 256, 131072, 32, 512);
    k_s_softmax<<<NB * 256, 64, 0, stream>>>(XM, Wp1, bp1, P1, 64);
    k_pool_t<256, 64, 128, 131072, 32, 512><<<NB * TC, 256, 0, stream>>>(P1, X, X1A);
    k_dflat<<<GRID(NB * 256), 256, 0, stream>>>(ADJ0, DFLAT, 256);
    k_adjp_t<256, 64, 128><<<NB * 8, 256, 0, stream>>>(ADJ0, P1, TMP);
    k_post_t<256, 64, 32, true><<<NB, 256, 0, stream>>>(P1, TMP, DFLAT, OADJ1, DFLAT2, MC, MC + 1);
    k_graphconv_t<64, 32><<<NB * TC, 256, 0, stream>>>(OADJ1, X1A, Wrel2, brel2, Wroot2, X1B);

    // ---- Level 2: Nc=64, Kc=32; x1b layout [B,T,64,32]: sb=32768, st=2048, sn=32
    k_mean_t<<<GRID(NB * 64 * HC), 256, 0, stream>>>(X1B, XM, 64, 32768, 2048, 32);
    k_s_softmax<<<NB * 64, 64, 0, stream>>>(XM, Wp2, bp2, P2, 32);
    k_pool_t<64, 32, 64, 32768, 2048, 32><<<NB * TC, 256, 0, stream>>>(P2, X1B, X2A);
    k_adjp_t<64, 32, 64><<<NB * 2, 256, 0, stream>>>(OADJ1, P2, TMP);
    k_post_t<64, 32, 64, true><<<NB, 256, 0, stream>>>(P2, TMP, DFLAT2, OADJ2, DFLAT3, MC, MC + 1);
    k_graphconv_t<32, 32><<<NB * TC, 256, 0, stream>>>(OADJ2, X2A, Wrel3, brel3, Wroot3, X2B);

    // ---- Level 3: Nc=32, Kc=8; x2b layout [B,T,32,32]: sb=16384, st=1024, sn=32
    k_mean_t<<<GRID(NB * 32 * HC), 256, 0, stream>>>(X2B, XM, 32, 16384, 1024, 32);
    k_s_softmax<<<NB * 32, 64, 0, stream>>>(XM, Wp3, bp3, P3, 8);
    k_pool_t<32, 8, 32, 16384, 1024, 32><<<NB * TC, 256, 0, stream>>>(P3, X2B, X3A);
    k_adjp_t<32, 8, 32><<<NB, 256, 0, stream>>>(OADJ2, P3, TMP);
    k_post_t<32, 8, 32, false><<<NB, 256, 0, stream>>>(P3, TMP, DFLAT3, OADJ3, DFLAT3, MC, MC + 1);
    k_graphconv_t<8, 64><<<NB * TC, 256, 0, stream>>>(OADJ3, X3A, Wrel4, brel4, Wroot4, out);

    // ---- agg = p1 @ (p2 @ p3)
    k_p23<<<GRID(NB * 64 * 8), 256, 0, stream>>>(P2, P3, P23);
    k_aggout<<<GRID(NB * 256 * 8), 256, 0, stream>>>(P1, P23, out + 524290);
}

// Round 4
// 331.052 us; speedup vs baseline: 5.0244x; 1.5828x over previous
//
#include <hip/hip_runtime.h>
#include <math.h>

#define NB 64
#define TC 16
#define HC 32
#define NNODES 16384
#define NEDGES 131072
#define EPSV 1e-15f

static inline int GRID(int n) { return (n + 255) / 256; }

template<int V> struct Log2 { static constexpr int v = 1 + Log2<V/2>::v; };
template<> struct Log2<1> { static constexpr int v = 0; };

// ---------------- GCN conv front-end ----------------

__global__ void k_init_deg(float* deg) {
    int i = blockIdx.x * 256 + threadIdx.x;
    if (i < NNODES) deg[i] = 1.0f;   // self-loop weight
}

__global__ void k_edge_deg(const int* __restrict__ dst, const float* __restrict__ ew,
                           float* __restrict__ deg) {
    int e = blockIdx.x * 256 + threadIdx.x;
    if (e < NEDGES) atomicAdd(&deg[dst[e]], ew[e]);
}

__global__ void k_rsqrt(float* deg) {
    int i = blockIdx.x * 256 + threadIdx.x;
    if (i < NNODES) { float d = deg[i]; deg[i] = (d > 0.f) ? rsqrtf(d) : 0.f; }
}

// fused: unweighted adj count (for mincut) + weighted adj coef (for GCN gather)
__global__ void k_build(const int* __restrict__ src, const int* __restrict__ dst,
                        const float* __restrict__ ew, const float* __restrict__ dinv,
                        float* __restrict__ adj, float* __restrict__ wadj) {
    int e = blockIdx.x * 256 + threadIdx.x;
    if (e >= NEDGES) return;
    int s = src[e], d = dst[e];
    int g = s >> 8, sl = s & 255, dl = d & 255;
    atomicAdd(&adj[((size_t)g << 16) + (sl << 8) + dl], 1.0f);
    float coef = dinv[s] * ew[e] * dinv[d];
    atomicAdd(&wadj[((size_t)g << 16) + (dl << 8) + sl], coef);
}

// z[b,d,0:48] = sum_s wadj[b,d,s] * pos[b,s,0:48]   ([256x256]@[256x48] per graph)
// grid NB*4 (64 d-rows per block); thread = (d = tid>>2, q = tid&3 -> 12 f's)
__global__ void k_zgemm(const float* __restrict__ wadj, const float* __restrict__ pos,
                        float* __restrict__ z) {
    __shared__ __align__(16) float as_[64 * 36];   // stride 36: 16B-aligned, ~2-way reads
    __shared__ __align__(16) float bs[32 * 48];
    int b = blockIdx.x >> 2;
    int dtile = (blockIdx.x & 3) * 64;
    int tid = threadIdx.x;
    int d = tid >> 2, q = tid & 3;
    float acc[12];
#pragma unroll
    for (int j = 0; j < 12; ++j) acc[j] = 0.f;
    const float* arow = wadj + ((size_t)b << 16) + (size_t)dtile * 256;
    const float* pbase = pos + (size_t)b * 256 * 48;
    for (int s0 = 0; s0 < 256; s0 += 32) {
        // stage A: 64 rows x 32 cols = 512 float4
        for (int i = tid; i < 512; i += 256) {
            int r = i >> 3, c = i & 7;
            *(float4*)(as_ + r * 36 + c * 4) =
                *(const float4*)(arow + (size_t)r * 256 + s0 + c * 4);
        }
        // stage B: 32 rows x 48 cols = 384 float4
        for (int i = tid; i < 384; i += 256) {
            int r = i / 12, c = i % 12;
            *(float4*)(bs + r * 48 + c * 4) =
                *(const float4*)(pbase + (size_t)(s0 + r) * 48 + c * 4);
        }
        __syncthreads();
#pragma unroll 8
        for (int sp = 0; sp < 32; ++sp) {
            float a = as_[d * 36 + sp];
            const float* bp = &bs[sp * 48 + q * 12];
#pragma unroll
            for (int j = 0; j < 12; ++j) acc[j] += a * bp[j];
        }
        __syncthreads();
    }
    float* zr = z + (size_t)(b * 256 + dtile + d) * 48 + q * 12;
#pragma unroll
    for (int j = 0; j < 12; ++j) zr[j] = acc[j];
}

// y[n,t,h] = relu((z[n,t,:] + pos[n,t,:]*dinv^2) @ W1[:,h] + b1[h])
__global__ void k_y(const float* __restrict__ z, const float* __restrict__ pos,
                    const float* __restrict__ dinv, const float* __restrict__ W1,
                    const float* __restrict__ b1, float* __restrict__ y) {
    int idx = blockIdx.x * 256 + threadIdx.x;
    if (idx >= NNODES * TC * HC) return;
    int h = idx & 31;
    int nt = idx >> 5;
    int n = nt >> 4, t = nt & 15;
    const float* zr = z + (size_t)n * 48 + t * 3;
    const float* pr = pos + (size_t)n * 48 + t * 3;
    float di = dinv[n], d2 = di * di;
    float a0 = zr[0] + pr[0] * d2;
    float a1 = zr[1] + pr[1] * d2;
    float a2 = zr[2] + pr[2] * d2;
    float v = a0 * W1[h] + a1 * W1[32 + h] + a2 * W1[64 + h] + b1[h];
    y[idx] = fmaxf(v, 0.0f);
}

// ---------------- level kernels ----------------

// xm[r,h] = mean_t x[b*sb + t*st + n*sn + h],  r = b*Nc+n
__global__ void k_mean_t(const float* __restrict__ x, float* __restrict__ xm,
                         int Nc, int sb, int st, int sn) {
    int idx = blockIdx.x * 256 + threadIdx.x;
    int total = NB * Nc * HC;
    if (idx >= total) return;
    int h = idx & 31;
    int r = idx >> 5;
    int b = r / Nc, n = r % Nc;
    const float* p = x + (size_t)b * sb + (size_t)n * sn + h;
    float s = 0.f;
    for (int t = 0; t < TC; ++t) s += p[(size_t)t * st];
    xm[idx] = s * (1.0f / TC);
}

// one 64-lane wave per row: s = tanh(xm@Wp + bp), p = softmax_k(s)
__global__ void k_s_softmax(const float* __restrict__ xm, const float* __restrict__ Wp,
                            const float* __restrict__ bp, float* __restrict__ p, int Kc) {
    int r = blockIdx.x;
    int k = threadIdx.x;
    const float* xr = xm + (size_t)r * HC;
    float v = -1e30f;
    if (k < Kc) {
        float acc = bp[k];
        for (int h = 0; h < HC; ++h) acc += xr[h] * Wp[h * Kc + k];
        v = tanhf(acc);
    }
    float m = v;
    for (int o = 32; o > 0; o >>= 1) m = fmaxf(m, __shfl_xor(m, o));
    float e = (k < Kc) ? expf(v - m) : 0.f;
    float s = e;
    for (int o = 32; o > 0; o >>= 1) s += __shfl_xor(s, o);
    if (k < Kc) p[(size_t)r * Kc + k] = e / s;
}

// out[b,t,k,h] = sum_n p[(b*NC+n)*KC+k] * x[b*SB + t*STT + n*STN + h]
template<int NC, int KC, int NCH, int SB, int STT, int STN>
__global__ void k_pool_t(const float* __restrict__ p, const float* __restrict__ x,
                         float* __restrict__ outp) {
    constexpr int KPT = KC / 8;
    __shared__ __align__(16) float xs[NCH * HC];
    __shared__ __align__(16) float ps[NCH * KC];
    int bt = blockIdx.x;
    int b = bt >> 4, t = bt & 15;
    int tid = threadIdx.x;
    int h = tid & 31;
    int k0 = (tid >> 5) * KPT;
    float acc[KPT];
#pragma unroll
    for (int j = 0; j < KPT; ++j) acc[j] = 0.f;
    const float* xbase = x + (size_t)b * SB + (size_t)t * STT;
    const float* pbase = p + (size_t)b * NC * KC;
    for (int n0 = 0; n0 < NC; n0 += NCH) {
        for (int i = tid; i < NCH * 8; i += 256) {
            int n = i >> 3, q = i & 7;
            ((float4*)xs)[i] = ((const float4*)(xbase + (size_t)(n0 + n) * STN))[q];
        }
        for (int i = tid; i < NCH * KC / 4; i += 256)
            ((float4*)ps)[i] = ((const float4*)(pbase + (size_t)n0 * KC))[i];
        __syncthreads();
#pragma unroll 4
        for (int n = 0; n < NCH; ++n) {
            float xv = xs[n * HC + h];
#pragma unroll
            for (int j = 0; j < KPT; ++j) acc[j] += ps[n * KC + k0 + j] * xv;
        }
        __syncthreads();
    }
#pragma unroll
    for (int j = 0; j < KPT; ++j)
        outp[((size_t)bt * KC + k0 + j) * HC + h] = acc[j];
}

__global__ void k_dflat(const float* __restrict__ adj, float* __restrict__ dflat, int Nc) {
    int idx = blockIdx.x * 256 + threadIdx.x;
    if (idx >= NB * Nc) return;
    const float* a = adj + (size_t)idx * Nc;
    float s = 0.f;
    for (int m = 0; m < Nc; ++m) s += a[m];
    dflat[idx] = s;
}

// tmp[b,n,l] = sum_m adj[b,n,m]*p[b,m,l]; block per (b, 32-n tile), LDS staged
template<int NC, int KC, int MCH>
__global__ void k_adjp_t(const float* __restrict__ adj, const float* __restrict__ p,
                         float* __restrict__ tmp) {
    constexpr int LPT = KC / 8;
    constexpr int MROW = MCH + 4;
    constexpr int MQ = MCH / 4;
    constexpr int NBK = NC / 32;
    __shared__ __align__(16) float ps[MCH * KC];
    __shared__ __align__(16) float as_[32 * MROW];
    int b = blockIdx.x / NBK;
    int nt0 = (blockIdx.x % NBK) * 32;
    int tid = threadIdx.x;
    int n = tid >> 3;
    int l0 = (tid & 7) * LPT;
    float acc[LPT];
#pragma unroll
    for (int j = 0; j < LPT; ++j) acc[j] = 0.f;
    for (int m0 = 0; m0 < NC; m0 += MCH) {
        for (int i = tid; i < MCH * KC / 4; i += 256)
            ((float4*)ps)[i] = ((const float4*)(p + ((size_t)b * NC + m0) * KC))[i];
        for (int i = tid; i < 32 * MQ; i += 256) {
            int r = i / MQ, q = i % MQ;
            ((float4*)(as_ + r * MROW))[q] =
                ((const float4*)(adj + ((size_t)b * NC + nt0 + r) * NC + m0))[q];
        }
        __syncthreads();
#pragma unroll 4
        for (int m = 0; m < MCH; ++m) {
            float av = as_[n * MROW + m];
#pragma unroll
            for (int j = 0; j < LPT; ++j) acc[j] += av * ps[m * KC + l0 + j];
        }
        __syncthreads();
    }
#pragma unroll
    for (int j = 0; j < LPT; ++j)
        tmp[((size_t)b * NC + nt0 + n) * KC + l0 + j] = acc[j];
}

__device__ inline float blk_sum256(float v, float* rbuf) {
    for (int o = 32; o > 0; o >>= 1) v += __shfl_xor(v, o);
    __syncthreads();
    if ((threadIdx.x & 63) == 0) rbuf[threadIdx.x >> 6] = v;
    __syncthreads();
    return rbuf[0] + rbuf[1] + rbuf[2] + rbuf[3];
}

// Fused: oadj = p^T tmp, ss = p^T p, losses, zero-diag+normalize, next dflat
template<int NC, int KC, int NCH, bool DFN>
__global__ void k_post_t(const float* __restrict__ p, const float* __restrict__ tmp,
                         const float* __restrict__ dflat, float* __restrict__ oadj_out,
                         float* __restrict__ dfn_out, float* __restrict__ mc_out,
                         float* __restrict__ or_out) {
    constexpr int LK = Log2<KC>::v;
    constexpr int KCP = KC + 1;
    constexpr int TW = KC / 4;
    constexpr int NT = TW * TW;
    __shared__ __align__(16) float ps[NCH * KC];
    __shared__ __align__(16) float ts[NCH * KC];
    __shared__ float sss[KC * KCP];
    __shared__ float oss[KC * KCP];
    __shared__ float dvv[KC];
    __shared__ float rbuf[4];
    int b = blockIdx.x, tid = threadIdx.x;
    const float* pb = p + (size_t)b * NC * KC;
    const float* tb = tmp + (size_t)b * NC * KC;
    const float* db = dflat + (size_t)b * NC;
    float sa[4][4], oa[4][4];
#pragma unroll
    for (int r = 0; r < 4; ++r)
#pragma unroll
        for (int c = 0; c < 4; ++c) { sa[r][c] = 0.f; oa[r][c] = 0.f; }
    int kt = (tid < NT) ? tid / TW : 0;
    int lt = (tid < NT) ? tid % TW : 0;
    float den = 0.f;
    for (int n0 = 0; n0 < NC; n0 += NCH) {
        for (int i = tid; i < NCH * KC / 4; i += 256) {
            ((float4*)ps)[i] = ((const float4*)(pb + (size_t)n0 * KC))[i];
            ((float4*)ts)[i] = ((const float4*)(tb + (size_t)n0 * KC))[i];
        }
        __syncthreads();
        for (int i4 = tid; i4 < NCH * KC / 4; i4 += 256) {
            float4 v = ((const float4*)ps)[i4];
            float dd = db[n0 + ((i4 * 4) >> LK)];
            den += (v.x * v.x + v.y * v.y + v.z * v.z + v.w * v.w) * dd;
        }
        if (tid < NT) {
#pragma unroll 4
            for (int nn = 0; nn < NCH; ++nn) {
                float4 kv4 = *(const float4*)&ps[nn * KC + kt * 4];
                float4 lv4 = *(const float4*)&ps[nn * KC + lt * 4];
                float4 tv4 = *(const float4*)&ts[nn * KC + lt * 4];
                float kv[4] = {kv4.x, kv4.y, kv4.z, kv4.w};
                float lv[4] = {lv4.x, lv4.y, lv4.z, lv4.w};
                float tv[4] = {tv4.x, tv4.y, tv4.z, tv4.w};
#pragma unroll
                for (int r = 0; r < 4; ++r)
#pragma unroll
                    for (int c = 0; c < 4; ++c) {
                        sa[r][c] += kv[r] * lv[c];
                        oa[r][c] += kv[r] * tv[c];
                    }
            }
        }
        __syncthreads();
    }
    if (tid < NT) {
#pragma unroll
        for (int r = 0; r < 4; ++r)
#pragma unroll
            for (int c = 0; c < 4; ++c) {
                sss[(kt * 4 + r) * KCP + lt * 4 + c] = sa[r][c];
                oss[(kt * 4 + r) * KCP + lt * 4 + c] = oa[r][c];
            }
    }
    __syncthreads();
    float ssn2 = 0.f;
    for (int i = tid; i < KC * KC; i += 256) {
        int k = i >> LK, l = i & (KC - 1);
        float v = sss[k * KCP + l];
        ssn2 += v * v;
    }
    float num = 0.f;
    for (int k = tid; k < KC; k += 256) num += oss[k * KCP + k];
    float den_t = blk_sum256(den, rbuf);
    float ssn2_t = blk_sum256(ssn2, rbuf);
    float num_t = blk_sum256(num, rbuf);
    float inv = 1.0f / sqrtf(ssn2_t);
    float dk = rsqrtf((float)KC);
    float o2 = 0.f;
    for (int i = tid; i < KC * KC; i += 256) {
        int k = i >> LK, l = i & (KC - 1);
        float v = sss[k * KCP + l] * inv - ((k == l) ? dk : 0.f);
        o2 += v * v;
    }
    float o2_t = blk_sum256(o2, rbuf);
    if (tid == 0) {
        atomicAdd(mc_out, -(num_t / den_t) * (1.0f / NB));
        atomicAdd(or_out, sqrtf(o2_t) * (1.0f / NB));
    }
    if (tid < KC) {
        float rs = 0.f;
        for (int l = 0; l < KC; ++l) rs += oss[tid * KCP + l];
        rs -= oss[tid * KCP + tid];
        dvv[tid] = sqrtf(rs) + EPSV;
    }
    __syncthreads();
    for (int i = tid; i < KC * KC; i += 256) {
        int k = i >> LK, l = i & (KC - 1);
        float v = (k == l) ? 0.f : oss[k * KCP + l] / (dvv[k] * dvv[l]);
        oadj_out[(size_t)b * KC * KC + i] = v;
    }
    if (DFN && tid < KC) {
        float s = 0.f;
        for (int l = 0; l < KC; ++l)
            if (l != tid) s += oss[tid * KCP + l] / (dvv[tid] * dvv[l]);
        dfn_out[(size_t)b * KC + tid] = s;
    }
}

// Fused dense_graph_conv per (b,t): out = (adjn@x)@Wrel + brel + x@Wroot
template<int NC2, int OC>
__global__ void k_graphconv_t(const float* __restrict__ adjn, const float* __restrict__ x,
                              const float* __restrict__ Wrel, const float* __restrict__ brel,
                              const float* __restrict__ Wroot, float* __restrict__ outp) {
    constexpr int EL1 = NC2 * HC / 256;
    constexpr int EL2 = NC2 * OC / 256;
    constexpr int LOC = Log2<OC>::v;
    __shared__ __align__(16) float xs[NC2 * HC];
    __shared__ __align__(16) float as_[NC2 * NC2];
    __shared__ float c1[NC2 * HC];
    int bt = blockIdx.x;
    int b = bt >> 4;
    int tid = threadIdx.x;
    for (int i = tid; i < NC2 * HC / 4; i += 256)
        ((float4*)xs)[i] = ((const float4*)(x + (size_t)bt * NC2 * HC))[i];
    for (int i = tid; i < NC2 * NC2 / 4; i += 256)
        ((float4*)as_)[i] = ((const float4*)(adjn + (size_t)b * NC2 * NC2))[i];
    __syncthreads();
#pragma unroll
    for (int e = 0; e < EL1; ++e) {
        int idx = tid + e * 256;
        int hh = idx & 31, n = idx >> 5;
        float acc = 0.f;
#pragma unroll 8
        for (int m = 0; m < NC2; ++m) acc += as_[n * NC2 + m] * xs[m * HC + hh];
        c1[idx] = acc;
    }
    __syncthreads();
#pragma unroll
    for (int e = 0; e < EL2; ++e) {
        int idx = tid + e * 256;
        int o = idx & (OC - 1), n = idx >> LOC;
        float acc = brel[o];
#pragma unroll 8
        for (int hh = 0; hh < HC; ++hh)
            acc += c1[n * HC + hh] * Wrel[hh * OC + o] + xs[n * HC + hh] * Wroot[hh * OC + o];
        outp[(size_t)bt * NC2 * OC + idx] = acc;
    }
}

// q[b,k,m] = sum_l p2[b,k,l] * p3[b,l,m]
__global__ void k_p23(const float* __restrict__ p2, const float* __restrict__ p3,
                      float* __restrict__ q) {
    int idx = blockIdx.x * 256 + threadIdx.x;
    if (idx >= NB * 64 * 8) return;
    int m = idx & 7;
    int rest = idx >> 3;
    int k = rest % 64;
    int b = rest / 64;
    const float* p2p = p2 + ((size_t)b * 64 + k) * 32;
    const float* p3p = p3 + (size_t)b * 32 * 8 + m;
    float s = 0.f;
    for (int l = 0; l < 32; ++l) s += p2p[l] * p3p[(size_t)l * 8];
    q[idx] = s;
}

// aggout[b,n,m] = sum_k p1[b,n,k] * q[b,k,m]
__global__ void k_aggout(const float* __restrict__ p1, const float* __restrict__ q,
                         float* __restrict__ outp) {
    int idx = blockIdx.x * 256 + threadIdx.x;
    if (idx >= NB * 256 * 8) return;
    int m = idx & 7;
    int rest = idx >> 3;
    int n = rest & 255;
    int b = rest >> 8;
    const float* pp = p1 + ((size_t)b * 256 + n) * 64;
    const float* qp = q + (size_t)b * 512 + m;
    float s = 0.f;
    for (int k = 0; k < 64; ++k) s += pp[k] * qp[(size_t)k * 8];
    outp[idx] = s;
}

// ---------------- host launch ----------------

extern "C" void kernel_launch(void* const* d_in, const int* in_sizes, int n_in,
                              void* d_out, int out_size, void* d_ws, size_t ws_size,
                              hipStream_t stream) {
    const float* pos    = (const float*)d_in[0];
    const float* ea     = (const float*)d_in[1];
    const int*   esrc   = (const int*)d_in[2];
    const int*   edst   = (const int*)d_in[3];
    const float* W1     = (const float*)d_in[4];
    const float* b1     = (const float*)d_in[5];
    const float* Wp1    = (const float*)d_in[6];
    const float* bp1    = (const float*)d_in[7];
    const float* Wrel2  = (const float*)d_in[8];
    const float* brel2  = (const float*)d_in[9];
    const float* Wroot2 = (const float*)d_in[10];
    const float* Wp2    = (const float*)d_in[11];
    const float* bp2    = (const float*)d_in[12];
    const float* Wrel3  = (const float*)d_in[13];
    const float* brel3  = (const float*)d_in[14];
    const float* Wroot3 = (const float*)d_in[15];
    const float* Wp3    = (const float*)d_in[16];
    const float* bp3    = (const float*)d_in[17];
    const float* Wrel4  = (const float*)d_in[18];
    const float* brel4  = (const float*)d_in[19];
    const float* Wroot4 = (const float*)d_in[20];
    float* out = (float*)d_out;

    char* w = (char*)d_ws;
    float* ADJ0 = (float*)w;                   // 16.7 MB unweighted adj (live thru L1)
    float* WADJ = (float*)(w + 16777216);      // 16.7 MB weighted adj (dead after zgemm)
    float* X    = (float*)(w + 33554432);      // 33.5 MB : y -> TMP
    char* sp    = w + 67108864;
    float* DINV   = (float*)(sp);
    float* XM     = (float*)(sp + 65536);
    float* DFLAT2 = (float*)(sp + 1114112);
    float* DFLAT3 = (float*)(sp + 1130496);
    float* P1     = (float*)(sp + 2162688);
    float* X1A    = (float*)(sp + 6356992);    // also Z overlay (Z dead before X1A write)
    float* OADJ1  = (float*)(sp + 14745600);
    float* P2     = (float*)(sp + 15794176);
    float* OADJ2  = (float*)(sp + 16318464);
    float* P3     = (float*)(sp + 16580608);
    float* X3A    = (float*)(sp + 16646144);
    float* OADJ3  = (float*)(sp + 17694720);
    float* DFLAT  = (float*)(sp + 17727488);
    float* P23    = (float*)(sp + 17793024);
    float* Z      = X1A;
    // overlays of the dead WADJ region (after GCN):
    float* X1B  = (float*)(w + 16777216);
    float* X2A  = (float*)(w + 25165824);
    float* X2B  = (float*)(w + 29360128);
    float* TMP  = X;                            // valid after X's last read (L1 pool)
    float* MC   = out + 524288;                 // [mincut_total, ortho_total]

    hipMemsetAsync(ADJ0, 0, 33554432ull, stream);           // ADJ0 + WADJ
    hipMemsetAsync(MC, 0, 8, stream);                       // loss accumulators

    // GCN conv: deg -> weighted dense adj -> z = Wadj@pos -> y = proj+self+relu
    k_init_deg<<<GRID(NNODES), 256, 0, stream>>>(DINV);
    k_edge_deg<<<GRID(NEDGES), 256, 0, stream>>>(edst, ea, DINV);
    k_rsqrt<<<GRID(NNODES), 256, 0, stream>>>(DINV);
    k_build<<<GRID(NEDGES), 256, 0, stream>>>(esrc, edst, ea, DINV, ADJ0, WADJ);
    k_zgemm<<<NB * 4, 256, 0, stream>>>(WADJ, pos, Z);
    k_y<<<GRID(NNODES * TC * HC), 256, 0, stream>>>(Z, pos, DINV, W1, b1, X);

    // ---- Level 1: Nc=256, Kc=64; x layout [N,T,H]: sb=131072, st=32, sn=512
    k_mean_t<<<GRID(NB * 256 * HC), 256, 0, stream>>>(X, XM, 256, 131072, 32, 512);
    k_s_softmax<<<NB * 256, 64, 0, stream>>>(XM, Wp1, bp1, P1, 64);
    k_pool_t<256, 64, 128, 131072, 32, 512><<<NB * TC, 256, 0, stream>>>(P1, X, X1A);
    k_dflat<<<GRID(NB * 256), 256, 0, stream>>>(ADJ0, DFLAT, 256);
    k_adjp_t<256, 64, 128><<<NB * 8, 256, 0, stream>>>(ADJ0, P1, TMP);
    k_post_t<256, 64, 32, true><<<NB, 256, 0, stream>>>(P1, TMP, DFLAT, OADJ1, DFLAT2, MC, MC + 1);
    k_graphconv_t<64, 32><<<NB * TC, 256, 0, stream>>>(OADJ1, X1A, Wrel2, brel2, Wroot2, X1B);

    // ---- Level 2: Nc=64, Kc=32; x1b layout [B,T,64,32]: sb=32768, st=2048, sn=32
    k_mean_t<<<GRID(NB * 64 * HC), 256, 0, stream>>>(X1B, XM, 64, 32768, 2048, 32);
    k_s_softmax<<<NB * 64, 64, 0, stream>>>(XM, Wp2, bp2, P2, 32);
    k_pool_t<64, 32, 64, 32768, 2048, 32><<<NB * TC, 256, 0, stream>>>(P2, X1B, X2A);
    k_adjp_t<64, 32, 64><<<NB * 2, 256, 0, stream>>>(OADJ1, P2, TMP);
    k_post_t<64, 32, 64, true><<<NB, 256, 0, stream>>>(P2, TMP, DFLAT2, OADJ2, DFLAT3, MC, MC + 1);
    k_graphconv_t<32, 32><<<NB * TC, 256, 0, stream>>>(OADJ2, X2A, Wrel3, brel3, Wroot3, X2B);

    // ---- Level 3: Nc=32, Kc=8; x2b layout [B,T,32,32]: sb=16384, st=1024, sn=32
    k_mean_t<<<GRID(NB * 32 * HC), 256, 0, stream>>>(X2B, XM, 32, 16384, 1024, 32);
    k_s_softmax<<<NB * 32, 64, 0, stream>>>(XM, Wp3, bp3, P3, 8);
    k_pool_t<32, 8, 32, 16384, 1024, 32><<<NB * TC, 256, 0, stream>>>(P3, X2B, X3A);
    k_adjp_t<32, 8, 32><<<NB, 256, 0, stream>>>(OADJ2, P3, TMP);
    k_post_t<32, 8, 32, false><<<NB, 256, 0, stream>>>(P3, TMP, DFLAT3, OADJ3, DFLAT3, MC, MC + 1);
    k_graphconv_t<8, 64><<<NB * TC, 256, 0, stream>>>(OADJ3, X3A, Wrel4, brel4, Wroot4, out);

    // ---- agg = p1 @ (p2 @ p3)
    k_p23<<<GRID(NB * 64 * 8), 256, 0, stream>>>(P2, P3, P23);
    k_aggout<<<GRID(NB * 256 * 8), 256, 0, stream>>>(P1, P23, out + 524290);
}